// Round 8
// baseline (1031.500 us; speedup 1.0000x reference)
//
#include <hip/hip_runtime.h>

#define NN 50000
#define NE 400000
#define NG 32
#define SLOPE 0.2f
#define NSB ((NN + 255) / 256)   // 196 scan blocks

typedef __attribute__((ext_vector_type(4))) float f32x4;
typedef __attribute__((ext_vector_type(16))) float f32x16;
typedef __attribute__((ext_vector_type(8))) short s16x8;

__device__ __forceinline__ float lrelu(float v) { return v > 0.f ? v : SLOPE * v; }
__device__ __forceinline__ unsigned short f2bf(float f) {
    union { float f; unsigned u; } c; c.f = f;
    unsigned r = c.u + 0x7fffu + ((c.u >> 16) & 1u);
    return (unsigned short)(r >> 16);
}
__device__ __forceinline__ float bf2f(unsigned short b) {
    union { unsigned u; float f; } c; c.u = ((unsigned)b) << 16; return c.f;
}
__device__ __forceinline__ uint2 pack_bf4(float a, float b, float c, float d) {
    uint2 u;
    u.x = (unsigned)f2bf(a) | ((unsigned)f2bf(b) << 16);
    u.y = (unsigned)f2bf(c) | ((unsigned)f2bf(d) << 16);
    return u;
}

// ---------------- CSR build ----------------
__global__ __launch_bounds__(256) void k_hist(const int* __restrict__ dst, int* __restrict__ deg) {
    int e = blockIdx.x * 256 + threadIdx.x;
    if (e < NE) atomicAdd(&deg[dst[e]], 1);
}

__global__ __launch_bounds__(256) void k_bsum(const int* __restrict__ deg, int* __restrict__ bsum) {
    __shared__ int ls[256];
    const int t = threadIdx.x;
    const int idx = blockIdx.x * 256 + t;
    ls[t] = (idx < NN) ? deg[idx] : 0;
    __syncthreads();
#pragma unroll
    for (int off = 128; off; off >>= 1) {
        if (t < off) ls[t] += ls[t + off];
        __syncthreads();
    }
    if (t == 0) bsum[blockIdx.x] = ls[0];
}

__global__ __launch_bounds__(256) void k_scan2(const int* __restrict__ deg,
                                               const int* __restrict__ bsum,
                                               int* __restrict__ rowptr, int* __restrict__ cursor) {
    __shared__ int lb[256];
    __shared__ int ls[256];
    const int t = threadIdx.x, b = blockIdx.x;
    lb[t] = (t < NSB && t < b) ? bsum[t] : 0;
    const int idx = b * 256 + t;
    const int v = (idx < NN) ? deg[idx] : 0;
    ls[t] = v;
    __syncthreads();
#pragma unroll
    for (int off = 128; off; off >>= 1) {
        if (t < off) lb[t] += lb[t + off];
        __syncthreads();
    }
#pragma unroll
    for (int off = 1; off < 256; off <<= 1) {
        int u = (t >= off) ? ls[t - off] : 0;
        __syncthreads();
        ls[t] += u;
        __syncthreads();
    }
    if (idx < NN) {
        const int run = lb[0] + ls[t] - v;
        rowptr[idx] = run;
        cursor[idx] = run;
    }
    if (b == 0 && t == 0) rowptr[NN] = NE;
}

__global__ __launch_bounds__(256) void k_perm(const int* __restrict__ dst,
                                              int* __restrict__ cursor, int* __restrict__ eid) {
    int e = blockIdx.x * 256 + threadIdx.x;
    if (e < NE) { int p = atomicAdd(&cursor[dst[e]], 1); eid[p] = e; }
}

// ---------------- one-time weight prep: bf16 + XOR-swizzle ----------------
__global__ __launch_bounds__(256) void k_wprep(const float* __restrict__ w3,
                                               const float* __restrict__ w2,
                                               const float* __restrict__ b3,
                                               unsigned short* __restrict__ w3t_g,
                                               unsigned short* __restrict__ w2t_g,
                                               unsigned short* __restrict__ b3t_g) {
    const int v = blockIdx.x * 256 + threadIdx.x;
    if (v < 64 * 512) {  // w3: v = k*512 + n -> w3t[n][k]
        const int k = v >> 9, n = v & 511;
        const int byte = (n << 7) | ((k << 1) ^ ((n & 7) << 4));
        *(unsigned short*)((char*)w3t_g + byte) = f2bf(w3[v]);
    }
    if (v < 128 * 64) {  // w2: v = j*64 + o -> w2t[o][j]
        const int j = v >> 6, o = v & 63;
        const int byte = (o << 8) | ((j << 1) ^ ((o & 7) << 4));
        *(unsigned short*)((char*)w2t_g + byte) = f2bf(w2[v]);
    }
    if (v < 512) {       // b3: v = i*32 + o -> b3t[o][i]
        const int i = v >> 5, o = v & 31;
        b3t_g[o * 16 + i] = f2bf(b3[v]);
    }
}

// ---------------- fused NNConv: L1 scalar -> L2 32x32 MFMA -> w3 32x32 MFMA -> msg ----------
// Chunk = 64 edges = 2 groups of 32. Lane role: e_local = g*32 + (lane&31), lg2 = lane>>5.
// L1 (scalar fp32): h1[e][j], j = kstep*16 + lg2*8 + idx -> directly the L2 B-fragment.
// L2: h2 = relu(w2^T@h1 + b2) via mfma_32x32x16 (A=w2t LDS, 16 A-reads reused for both groups).
// D layout (verified): col=lane&31, row=(reg&3)+8*(reg>>2)+4*lg2 -> o2 = nblk*32+row.
// h2 -> slab (swizzled) -> w3 B-frags. Seed p = mfma(b3t, x_bf16). w3 GEMM: 16 nblk x 4 kstep,
// A-read reused across groups; i = nblk (wave-uniform) -> p += x[nblk] * D. msg via slab transpose.
#define FUSED_GRID 256
__global__ __launch_bounds__(512) void k_fused(
    const float* __restrict__ ea,
    const float* __restrict__ w1, const float* __restrict__ b1,
    const unsigned short* __restrict__ w2t_g, const float* __restrict__ b2,
    const unsigned short* __restrict__ w3t_g, const unsigned short* __restrict__ b3t_g,
    const int* __restrict__ src, const float* __restrict__ x,
    unsigned short* __restrict__ msg)
{
    __shared__ __align__(16) unsigned short w3t[512 * 64];  // 64 KB
    __shared__ __align__(16) unsigned short w2t[64 * 128];  // 16 KB
    __shared__ __align__(16) unsigned short b3t[512];       // 1 KB
    __shared__ __align__(16) float w1s[384];
    __shared__ __align__(16) float b1s[128];
    __shared__ __align__(16) float b2s[64];
    __shared__ __align__(16) unsigned slab[8][2048];        // 8 KB per wave

    const int t = threadIdx.x;
    {
        const uint4* g = (const uint4*)w3t_g;
        uint4* l = (uint4*)w3t;
        for (int v = t; v < 4096; v += 512) l[v] = g[v];
        const uint4* g2 = (const uint4*)w2t_g;
        uint4* l2 = (uint4*)w2t;
        for (int v = t; v < 1024; v += 512) l2[v] = g2[v];
    }
    if (t < 64) ((uint4*)b3t)[t] = ((const uint4*)b3t_g)[t];
    if (t < 384) w1s[t] = w1[t];
    if (t < 128) b1s[t] = b1[t];
    if (t < 64)  b2s[t] = b2[t];
    __syncthreads();

    const int wid = t >> 6, lane = t & 63;
    const int l31 = lane & 31, lg2 = lane >> 5;
    char* sw = (char*)slab[wid];

    for (int chunk = blockIdx.x * 8 + wid; chunk < NE / 64; chunk += FUSED_GRID * 8) {
        const int eA = chunk * 64 + l31;
        const int eB = eA + 32;

        // issue gathers early
        const int snA = src[eA], snB = src[eB];
        const float eaA0 = ea[eA * 3], eaA1 = ea[eA * 3 + 1], eaA2 = ea[eA * 3 + 2];
        const float eaB0 = ea[eB * 3], eaB1 = ea[eB * 3 + 1], eaB2 = ea[eB * 3 + 2];
        const f32x4* __restrict__ xpA = (const f32x4*)(x + (size_t)snA * 16);
        const f32x4* __restrict__ xpB = (const f32x4*)(x + (size_t)snB * 16);
        f32x4 xA0 = xpA[0], xA1 = xpA[1], xA2 = xpA[2], xA3 = xpA[3];
        f32x4 xB0 = xpB[0], xB1 = xpB[1], xB2 = xpB[2], xB3 = xpB[3];

        // ---- L1 scalar: h1 B-fragments, j = kstep*16 + lg2*8 + idx ----
        s16x8 hbA[8], hbB[8];
#pragma unroll
        for (int kstep = 0; kstep < 8; ++kstep) {
            const int j0 = kstep * 16 + lg2 * 8;
            f32x4 wa0 = *(const f32x4*)(w1s + j0),       wa1 = *(const f32x4*)(w1s + j0 + 4);
            f32x4 wb0 = *(const f32x4*)(w1s + 128 + j0), wb1 = *(const f32x4*)(w1s + 128 + j0 + 4);
            f32x4 wc0 = *(const f32x4*)(w1s + 256 + j0), wc1 = *(const f32x4*)(w1s + 256 + j0 + 4);
            f32x4 bv0 = *(const f32x4*)(b1s + j0),       bv1 = *(const f32x4*)(b1s + j0 + 4);
#pragma unroll
            for (int i = 0; i < 4; ++i) {
                float hA0 = fmaf(eaA0, wa0[i], fmaf(eaA1, wb0[i], fmaf(eaA2, wc0[i], bv0[i])));
                float hA1 = fmaf(eaA0, wa1[i], fmaf(eaA1, wb1[i], fmaf(eaA2, wc1[i], bv1[i])));
                float hB0 = fmaf(eaB0, wa0[i], fmaf(eaB1, wb0[i], fmaf(eaB2, wc0[i], bv0[i])));
                float hB1 = fmaf(eaB0, wa1[i], fmaf(eaB1, wb1[i], fmaf(eaB2, wc1[i], bv1[i])));
                hbA[kstep][i]     = (short)f2bf(fmaxf(hA0, 0.f));
                hbA[kstep][i + 4] = (short)f2bf(fmaxf(hA1, 0.f));
                hbB[kstep][i]     = (short)f2bf(fmaxf(hB0, 0.f));
                hbB[kstep][i + 4] = (short)f2bf(fmaxf(hB1, 0.f));
            }
        }

        // ---- L2: h2 = relu(w2^T@h1 + b2), A-reads shared across groups ----
        asm volatile("s_waitcnt lgkmcnt(0)" ::: "memory");  // prior chunk's slab reads done
#pragma unroll
        for (int nblk = 0; nblk < 2; ++nblk) {
            f32x16 accA, accB;
#pragma unroll
            for (int rh = 0; rh < 4; ++rh) {
                f32x4 bv = *(const f32x4*)(b2s + nblk * 32 + rh * 8 + lg2 * 4);
#pragma unroll
                for (int rq = 0; rq < 4; ++rq) { accA[rh * 4 + rq] = bv[rq]; accB[rh * 4 + rq] = bv[rq]; }
            }
            const int o = nblk * 32 + l31;
            const char* __restrict__ w2row = (const char*)w2t + (o << 8);
            const int sw2 = (o & 7) << 4;
#pragma unroll
            for (int kstep = 0; kstep < 8; ++kstep) {
                s16x8 a = *(const s16x8*)(w2row + ((kstep * 32 + lg2 * 16) ^ sw2));
                accA = __builtin_amdgcn_mfma_f32_32x32x16_bf16(a, hbA[kstep], accA, 0, 0, 0);
                accB = __builtin_amdgcn_mfma_f32_32x32x16_bf16(a, hbB[kstep], accB, 0, 0, 0);
            }
            // relu + pack + slab write: h2[e][o2], o2 = nblk*32 + rh*8 + lg2*4 + rq
            const int swA = (eA & 7) << 4, swB = (eB & 7) << 4;
#pragma unroll
            for (int rh = 0; rh < 4; ++rh) {
                const int kb = nblk * 64 + rh * 16 + lg2 * 8;
                *(uint2*)(sw + l31 * 128 + (kb ^ swA)) =
                    pack_bf4(fmaxf(accA[rh * 4], 0.f), fmaxf(accA[rh * 4 + 1], 0.f),
                             fmaxf(accA[rh * 4 + 2], 0.f), fmaxf(accA[rh * 4 + 3], 0.f));
                *(uint2*)(sw + (l31 + 32) * 128 + (kb ^ swB)) =
                    pack_bf4(fmaxf(accB[rh * 4], 0.f), fmaxf(accB[rh * 4 + 1], 0.f),
                             fmaxf(accB[rh * 4 + 2], 0.f), fmaxf(accB[rh * 4 + 3], 0.f));
            }
        }
        asm volatile("s_waitcnt lgkmcnt(0)" ::: "memory");  // h2 slab visible wave-wide

        // ---- w3 B-fragments from slab ----
        s16x8 wba[4], wbb[4];
        {
            const int swA = (l31 & 7) << 4, swB = swA;  // (eB&7)==(l31&7)
#pragma unroll
            for (int kstep = 0; kstep < 4; ++kstep) {
                const int kb = (kstep * 32 + lg2 * 16);
                wba[kstep] = *(const s16x8*)(sw + l31 * 128 + (kb ^ swA));
                wbb[kstep] = *(const s16x8*)(sw + (l31 + 32) * 128 + (kb ^ swB));
            }
        }

        // ---- seed: p = mfma(b3t, x_bf16) ----
        s16x8 b3f = *(const s16x8*)((const char*)b3t + l31 * 32 + lg2 * 16);
        s16x8 xbfA, xbfB;
        {
            f32x4 a0 = lg2 ? xA2 : xA0, a1 = lg2 ? xA3 : xA1;
            f32x4 b0 = lg2 ? xB2 : xB0, b1v = lg2 ? xB3 : xB1;
#pragma unroll
            for (int i = 0; i < 4; ++i) {
                xbfA[i] = (short)f2bf(a0[i]); xbfA[i + 4] = (short)f2bf(a1[i]);
                xbfB[i] = (short)f2bf(b0[i]); xbfB[i + 4] = (short)f2bf(b1v[i]);
            }
        }
        f32x16 pA = {0}, pB = {0};
        pA = __builtin_amdgcn_mfma_f32_32x32x16_bf16(b3f, xbfA, pA, 0, 0, 0);
        pB = __builtin_amdgcn_mfma_f32_32x32x16_bf16(b3f, xbfB, pB, 0, 0, 0);

        // ---- w3 GEMM: 16 nblk x 4 kstep, i = nblk ----
        const int n = l31;  // row within nblk
#pragma unroll
        for (int nblk = 0; nblk < 16; ++nblk) {
            const int nr = nblk * 32 + n;
            const char* __restrict__ arow = (const char*)w3t + (nr << 7);
            const int sw3 = (nr & 7) << 4;
            f32x16 dA = {0}, dB = {0};
#pragma unroll
            for (int kstep = 0; kstep < 4; ++kstep) {
                s16x8 a = *(const s16x8*)(arow + ((kstep * 32 + lg2 * 16) ^ sw3));
                dA = __builtin_amdgcn_mfma_f32_32x32x16_bf16(a, wba[kstep], dA, 0, 0, 0);
                dB = __builtin_amdgcn_mfma_f32_32x32x16_bf16(a, wbb[kstep], dB, 0, 0, 0);
            }
            const float xsA = (nblk < 4 ? xA0 : nblk < 8 ? xA1 : nblk < 12 ? xA2 : xA3)[nblk & 3];
            const float xsB = (nblk < 4 ? xB0 : nblk < 8 ? xB1 : nblk < 12 ? xB2 : xB3)[nblk & 3];
#pragma unroll
            for (int r = 0; r < 16; ++r) {
                pA[r] = fmaf(xsA, dA[r], pA[r]);
                pB[r] = fmaf(xsB, dB[r], pB[r]);
            }
        }

        // ---- msg via slab transpose: o = (r&3) + 8*(r>>2) + 4*lg2 ----
        asm volatile("s_waitcnt lgkmcnt(0)" ::: "memory");
#pragma unroll
        for (int rh = 0; rh < 4; ++rh) {
            const int ob = rh * 16 + lg2 * 8;
            *(uint2*)(sw + l31 * 64 + (ob ^ ((l31 & 7) << 3))) =
                pack_bf4(pA[rh * 4], pA[rh * 4 + 1], pA[rh * 4 + 2], pA[rh * 4 + 3]);
            *(uint2*)(sw + (l31 + 32) * 64 + (ob ^ ((l31 & 7) << 3))) =
                pack_bf4(pB[rh * 4], pB[rh * 4 + 1], pB[rh * 4 + 2], pB[rh * 4 + 3]);
        }
        asm volatile("s_waitcnt lgkmcnt(0)" ::: "memory");
#pragma unroll
        for (int q = 0; q < 4; ++q) {
            const int er = (lane >> 2) + q * 16;
            const int off = (lane & 3) * 16;
            const int s8 = (er & 7) << 3;
            uint2 a = *(const uint2*)(sw + er * 64 + (off ^ s8));
            uint2 b = *(const uint2*)(sw + er * 64 + ((off + 8) ^ s8));
            *(uint4*)((char*)msg + (size_t)chunk * 4096 + q * 1024 + lane * 16) =
                make_uint4(a.x, a.y, b.x, b.y);
        }
    }
}

// ---------------- aggregate msg by dst (CSR gather) + root transform ----------------
__global__ __launch_bounds__(256) void k_agg(
    const unsigned short* __restrict__ msg, const int* __restrict__ rowptr,
    const int* __restrict__ eid, const float* __restrict__ x,
    const float* __restrict__ rw, const float* __restrict__ cb, float* __restrict__ h1)
{
    const int gid = blockIdx.x * 256 + threadIdx.x;
    const int n = (gid >> 6) * 2 + ((gid & 63) >> 5);
    if (n >= NN) return;
    const int o = gid & 31;
    const int r0 = rowptr[n], r1 = rowptr[n + 1];
    float acc = 0.f;
    for (int j = r0; j < r1; ++j)
        acc += bf2f(msg[(size_t)eid[j] * 32 + o]);
    const float* __restrict__ xr = x + (size_t)n * 16;
    float root = cb[o];
#pragma unroll
    for (int i = 0; i < 16; ++i) root = fmaf(xr[i], rw[i * 32 + o], root);
    h1[(size_t)n * 32 + o] = fmaxf(acc + root, 0.f);
}

// ---------------- GAT: node transform + attention coefficients ----------------
template <int FI>
__global__ __launch_bounds__(256) void k_gat_h(
    const float* __restrict__ hin, const float* __restrict__ W,
    const float* __restrict__ av_s, const float* __restrict__ av_d,
    float* __restrict__ h, float* __restrict__ as_v, float* __restrict__ ad_v)
{
    const int n = blockIdx.x * 256 + threadIdx.x;
    if (n >= NN) return;
    float acc[64];
#pragma unroll
    for (int o = 0; o < 64; ++o) acc[o] = 0.f;
    const f32x4* __restrict__ hp = (const f32x4*)(hin + (size_t)n * FI);
#pragma unroll 2
    for (int i4 = 0; i4 < FI / 4; ++i4) {
        f32x4 xi = hp[i4];
#pragma unroll
        for (int c = 0; c < 4; ++c) {
            const float xv = xi[c];
            const float* __restrict__ wr = W + (i4 * 4 + c) * 64;
#pragma unroll
            for (int o = 0; o < 64; ++o) acc[o] = fmaf(xv, wr[o], acc[o]);
        }
    }
    float s = 0.f, d = 0.f;
#pragma unroll
    for (int o = 0; o < 64; ++o) {
        h[(size_t)n * 64 + o] = acc[o];
        s = fmaf(acc[o], av_s[o], s);
        d = fmaf(acc[o], av_d[o], d);
    }
    as_v[n] = s;
    ad_v[n] = d;
}

// ---------------- GAT: per-node softmax + weighted gather (one wave per node) ----------------
__global__ __launch_bounds__(256) void k_gat_node(
    const int* __restrict__ rowptr, const int* __restrict__ eid, const int* __restrict__ src,
    const float* __restrict__ h, const float* __restrict__ as_v, const float* __restrict__ ad_v,
    const float* __restrict__ b, float* __restrict__ out)
{
    const int n = (blockIdx.x * 256 + threadIdx.x) >> 6;
    if (n >= NN) return;
    const int lane = threadIdx.x & 63;
    const int r0 = rowptr[n], r1 = rowptr[n + 1];
    const float adn = ad_v[n];
    const float l_self = lrelu(as_v[n] + adn);
    float m = l_self;
    for (int j = r0 + lane; j < r1; j += 64)
        m = fmaxf(m, lrelu(as_v[src[eid[j]]] + adn));
#pragma unroll
    for (int off = 32; off; off >>= 1) m = fmaxf(m, __shfl_xor(m, off));
    float s = 0.f;
    for (int j = r0 + lane; j < r1; j += 64)
        s += expf(lrelu(as_v[src[eid[j]]] + adn) - m);
#pragma unroll
    for (int off = 32; off; off >>= 1) s += __shfl_xor(s, off);
    const float w_self = expf(l_self - m);
    s += w_self;
    float acc = w_self * h[(size_t)n * 64 + lane];
    for (int j = r0; j < r1; ++j) {
        const int sn = src[eid[j]];
        const float w = expf(lrelu(as_v[sn] + adn) - m);
        acc = fmaf(w, h[(size_t)sn * 64 + lane], acc);
    }
    out[(size_t)n * 64 + lane] = fmaxf(acc / s + b[lane], 0.f);
}

// ---------------- global mean pool ----------------
__global__ __launch_bounds__(256) void k_pool1(
    const float* __restrict__ h, const int* __restrict__ batch,
    float* __restrict__ gsum, float* __restrict__ gcnt)
{
    __shared__ float ls[NG * 64];
    __shared__ float lc[NG];
    for (int j = threadIdx.x; j < NG * 64; j += 256) ls[j] = 0.f;
    if (threadIdx.x < NG) lc[threadIdx.x] = 0.f;
    __syncthreads();
    const int base = blockIdx.x * 512;
    for (int idx = threadIdx.x; idx < 512 * 64; idx += 256) {
        const int nl = idx >> 6, f = idx & 63;
        const int n = base + nl;
        if (n < NN) {
            const int g = batch[n];
            atomicAdd(&ls[g * 64 + f], h[(size_t)n * 64 + f]);
            if (f == 0) atomicAdd(&lc[g], 1.f);
        }
    }
    __syncthreads();
    for (int j = threadIdx.x; j < NG * 64; j += 256) atomicAdd(&gsum[j], ls[j]);
    if (threadIdx.x < NG) atomicAdd(&gcnt[threadIdx.x], lc[threadIdx.x]);
}

__global__ __launch_bounds__(256) void k_pool2(
    const float* __restrict__ gsum, const float* __restrict__ gcnt, float* __restrict__ out)
{
    const int idx = blockIdx.x * 256 + threadIdx.x;
    if (idx >= NG * 64) return;
    out[idx] = gsum[idx] / fmaxf(gcnt[idx >> 6], 1.f);
}

extern "C" void kernel_launch(void* const* d_in, const int* in_sizes, int n_in,
                              void* d_out, int out_size, void* d_ws, size_t ws_size,
                              hipStream_t stream)
{
    const float* x     = (const float*)d_in[0];
    const float* ea    = (const float*)d_in[1];
    const int*   ei    = (const int*)d_in[2];
    const int*   batch = (const int*)d_in[3];
    const float* w1 = (const float*)d_in[4];   const float* b1 = (const float*)d_in[5];
    const float* w2 = (const float*)d_in[6];   const float* b2 = (const float*)d_in[7];
    const float* w3 = (const float*)d_in[8];   const float* b3 = (const float*)d_in[9];
    const float* rw = (const float*)d_in[10];  const float* cb = (const float*)d_in[11];
    const float* g1w  = (const float*)d_in[12]; const float* g1as = (const float*)d_in[13];
    const float* g1ad = (const float*)d_in[14]; const float* g1b  = (const float*)d_in[15];
    const float* g2w  = (const float*)d_in[16]; const float* g2as = (const float*)d_in[17];
    const float* g2ad = (const float*)d_in[18]; const float* g2b  = (const float*)d_in[19];
    const int* src = ei;
    const int* dst = ei + NE;
    float* out = (float*)d_out;
    (void)in_sizes; (void)n_in; (void)out_size; (void)ws_size;

    char* ws = (char*)d_ws;
    size_t off = 0;
    auto alloc = [&](size_t bytes) -> char* {
        char* p = ws + off;
        off += (bytes + 255) & ~(size_t)255;
        return p;
    };
    int*  deg    = (int*)alloc((size_t)NN * 4);
    int*  cursor = (int*)alloc((size_t)NN * 4);
    int*  rowptr = (int*)alloc((size_t)(NN + 1) * 4);
    int*  bsum   = (int*)alloc((size_t)NSB * 4);
    int*  eid    = (int*)alloc((size_t)NE * 4);
    unsigned short* w3t_g = (unsigned short*)alloc((size_t)64 * 512 * 2);
    unsigned short* w2t_g = (unsigned short*)alloc((size_t)64 * 128 * 2);
    unsigned short* b3t_g = (unsigned short*)alloc((size_t)512 * 2);
    unsigned short* msg   = (unsigned short*)alloc((size_t)NE * 32 * 2);  // 25.6 MB
    float* h1   = (float*)alloc((size_t)NN * 32 * 4);
    float* hB   = (float*)alloc((size_t)NN * 64 * 4);
    float* hC   = (float*)alloc((size_t)NN * 64 * 4);
    float* hD   = (float*)alloc((size_t)NN * 64 * 4);
    float* as_v = (float*)alloc((size_t)NN * 4);
    float* ad_v = (float*)alloc((size_t)NN * 4);
    float* gsum = (float*)alloc((size_t)NG * 64 * 4);
    float* gcnt = (float*)alloc((size_t)NG * 4);

    hipMemsetAsync(deg, 0, (size_t)NN * 4, stream);
    hipMemsetAsync(gsum, 0, (size_t)NG * 64 * 4, stream);
    hipMemsetAsync(gcnt, 0, (size_t)NG * 4, stream);

    // CSR build (parallel hierarchical scan)
    k_hist<<<(NE + 255) / 256, 256, 0, stream>>>(dst, deg);
    k_bsum<<<NSB, 256, 0, stream>>>(deg, bsum);
    k_scan2<<<NSB, 256, 0, stream>>>(deg, bsum, rowptr, cursor);
    k_perm<<<(NE + 255) / 256, 256, 0, stream>>>(dst, cursor, eid);

    // NNConv (fused MLP + GEMM, 32x32 MFMA)
    k_wprep<<<(64 * 512 + 255) / 256, 256, 0, stream>>>(w3, w2, b3, w3t_g, w2t_g, b3t_g);
    k_fused<<<FUSED_GRID, 512, 0, stream>>>(ea, w1, b1, w2t_g, b2, w3t_g, b3t_g, src, x, msg);
    k_agg<<<(NN / 2 * 64 + 255) / 256 + 1, 256, 0, stream>>>(msg, rowptr, eid, x, rw, cb, h1);

    // GAT layer 1
    k_gat_h<32><<<(NN + 255) / 256, 256, 0, stream>>>(h1, g1w, g1as, g1ad, hB, as_v, ad_v);
    k_gat_node<<<(NN * 64 + 255) / 256, 256, 0, stream>>>(rowptr, eid, src, hB, as_v, ad_v, g1b, hC);

    // GAT layer 2
    k_gat_h<64><<<(NN + 255) / 256, 256, 0, stream>>>(hC, g2w, g2as, g2ad, hB, as_v, ad_v);
    k_gat_node<<<(NN * 64 + 255) / 256, 256, 0, stream>>>(rowptr, eid, src, hB, as_v, ad_v, g2b, hD);

    // pool
    k_pool1<<<(NN + 511) / 512, 256, 0, stream>>>(hD, batch, gsum, gcnt);
    k_pool2<<<(NG * 64 + 255) / 256, 256, 0, stream>>>(gsum, gcnt, out);
}

// Round 9
// 406.152 us; speedup vs baseline: 2.5397x; 2.5397x over previous
//
#include <hip/hip_runtime.h>

#define NN 50000
#define NE 400000
#define NG 32
#define SLOPE 0.2f
#define NSB ((NN + 255) / 256)   // 196 scan blocks

typedef __attribute__((ext_vector_type(4))) float f32x4;
typedef __attribute__((ext_vector_type(16))) float f32x16;
typedef __attribute__((ext_vector_type(8))) short s16x8;

__device__ __forceinline__ float lrelu(float v) { return v > 0.f ? v : SLOPE * v; }
__device__ __forceinline__ unsigned short f2bf(float f) {
    union { float f; unsigned u; } c; c.f = f;
    unsigned r = c.u + 0x7fffu + ((c.u >> 16) & 1u);
    return (unsigned short)(r >> 16);
}
__device__ __forceinline__ float bf2f(unsigned short b) {
    union { unsigned u; float f; } c; c.u = ((unsigned)b) << 16; return c.f;
}
__device__ __forceinline__ uint2 pack_bf4(float a, float b, float c, float d) {
    uint2 u;
    u.x = (unsigned)f2bf(a) | ((unsigned)f2bf(b) << 16);
    u.y = (unsigned)f2bf(c) | ((unsigned)f2bf(d) << 16);
    return u;
}

// ---------------- CSR build ----------------
__global__ __launch_bounds__(256) void k_hist(const int* __restrict__ dst, int* __restrict__ deg) {
    int e = blockIdx.x * 256 + threadIdx.x;
    if (e < NE) atomicAdd(&deg[dst[e]], 1);
}

__global__ __launch_bounds__(256) void k_bsum(const int* __restrict__ deg, int* __restrict__ bsum) {
    __shared__ int ls[256];
    const int t = threadIdx.x;
    const int idx = blockIdx.x * 256 + t;
    ls[t] = (idx < NN) ? deg[idx] : 0;
    __syncthreads();
#pragma unroll
    for (int off = 128; off; off >>= 1) {
        if (t < off) ls[t] += ls[t + off];
        __syncthreads();
    }
    if (t == 0) bsum[blockIdx.x] = ls[0];
}

__global__ __launch_bounds__(256) void k_scan2(const int* __restrict__ deg,
                                               const int* __restrict__ bsum,
                                               int* __restrict__ rowptr, int* __restrict__ cursor) {
    __shared__ int lb[256];
    __shared__ int ls[256];
    const int t = threadIdx.x, b = blockIdx.x;
    lb[t] = (t < NSB && t < b) ? bsum[t] : 0;
    const int idx = b * 256 + t;
    const int v = (idx < NN) ? deg[idx] : 0;
    ls[t] = v;
    __syncthreads();
#pragma unroll
    for (int off = 128; off; off >>= 1) {
        if (t < off) lb[t] += lb[t + off];
        __syncthreads();
    }
#pragma unroll
    for (int off = 1; off < 256; off <<= 1) {
        int u = (t >= off) ? ls[t - off] : 0;
        __syncthreads();
        ls[t] += u;
        __syncthreads();
    }
    if (idx < NN) {
        const int run = lb[0] + ls[t] - v;
        rowptr[idx] = run;
        cursor[idx] = run;
    }
    if (b == 0 && t == 0) rowptr[NN] = NE;
}

__global__ __launch_bounds__(256) void k_perm(const int* __restrict__ dst,
                                              int* __restrict__ cursor, int* __restrict__ eid) {
    int e = blockIdx.x * 256 + threadIdx.x;
    if (e < NE) { int p = atomicAdd(&cursor[dst[e]], 1); eid[p] = e; }
}

// ---------------- one-time weight prep ----------------
// w3t: [n][k] bf16, XOR-swizzled.  w2t: [o][k_slot] bf16 swizzled, with the k-permutation
// that matches the L1-MFMA D-register order: k_phys(slot) = 32n + (j&3) + 8*(j>>2) + 16s + 4*lg2
// where slot = ks*16+lg2*8+j, n=ks>>1, s=ks&1.  w1p: [j][16] bf16 = [w1 | b1 | 0...].
// b3t: [o][16] bf16 = b3 transposed.
__global__ __launch_bounds__(256) void k_wprep(const float* __restrict__ w3,
                                               const float* __restrict__ w2,
                                               const float* __restrict__ w1,
                                               const float* __restrict__ b1,
                                               const float* __restrict__ b3,
                                               unsigned short* __restrict__ w3t_g,
                                               unsigned short* __restrict__ w2t_g,
                                               unsigned short* __restrict__ w1p_g,
                                               unsigned short* __restrict__ b3t_g) {
    const int v = blockIdx.x * 256 + threadIdx.x;
    if (v < 64 * 512) {  // w3: v = k*512 + n -> w3t[n][k]
        const int k = v >> 9, n = v & 511;
        const int byte = (n << 7) | ((k << 1) ^ ((n & 7) << 4));
        *(unsigned short*)((char*)w3t_g + byte) = f2bf(w3[v]);
    }
    if (v < 64 * 128) {  // w2t[o][slot]
        const int o = v & 63, slot = v >> 6;
        const int ks = slot >> 4, lg2 = (slot >> 3) & 1, j = slot & 7;
        const int kp = (ks >> 1) * 32 + (j & 3) + 8 * (j >> 2) + 16 * (ks & 1) + 4 * lg2;
        const int byte = (o << 8) | ((slot << 1) ^ ((o & 7) << 4));
        *(unsigned short*)((char*)w2t_g + byte) = f2bf(w2[kp * 64 + o]);
    }
    if (v < 128 * 16) {  // w1p[j][k]
        const int j = v >> 4, k = v & 15;
        float val = (k < 3) ? w1[k * 128 + j] : (k == 3 ? b1[j] : 0.f);
        w1p_g[v] = f2bf(val);
    }
    if (v < 512) {       // b3t[o][i]
        const int i = v >> 5, o = v & 31;
        b3t_g[o * 16 + i] = f2bf(b3[v]);
    }
}

// ---------------- fused NNConv, all-MFMA, 32 edges per chunk ----------------
// Lane role: edge = chunk*32 + l31, lg2 = lane>>5.
// L1: h1 = relu([w1|b1] @ [ea|1]) via 4 MFMAs (A=w1p regs, invariant); D rows packed into
//     the L2 B-fragments hb[8] using the compile-time r-map (j&3)+4*(j>>2)+8s.
// L2: h2 = relu(w2t @ h1 + b2) via 16 MFMAs (A from LDS, k-perm pre-applied); D -> slab.
// Seed: p = mfma(b3t, x_bf16). w3 GEMM: 16 nblk x 4 ks; i = nblk wave-uniform -> p += x[i]*D.
// msg via slab transpose, one contiguous 1KB store per chunk.
#define FUSED_GRID 256
#define NCHUNK (NE / 32)
__global__ __launch_bounds__(512, 1) void k_fused(
    const float* __restrict__ ea,
    const unsigned short* __restrict__ w1p_g,
    const unsigned short* __restrict__ w2t_g, const float* __restrict__ b2,
    const unsigned short* __restrict__ w3t_g, const unsigned short* __restrict__ b3t_g,
    const int* __restrict__ src, const float* __restrict__ x,
    unsigned short* __restrict__ msg)
{
    __shared__ __align__(16) unsigned short w3t[512 * 64];  // 64 KB
    __shared__ __align__(16) unsigned short w2t[64 * 128];  // 16 KB
    __shared__ __align__(16) unsigned short w1p[128 * 16];  // 4 KB
    __shared__ __align__(16) unsigned short b3t[512];       // 1 KB
    __shared__ __align__(16) unsigned slab[8][1024];        // 4 KB per wave

    const int t = threadIdx.x;
    {
        const uint4* g = (const uint4*)w3t_g;
        uint4* l = (uint4*)w3t;
        for (int v = t; v < 4096; v += 512) l[v] = g[v];
        const uint4* g2 = (const uint4*)w2t_g;
        uint4* l2 = (uint4*)w2t;
        for (int v = t; v < 1024; v += 512) l2[v] = g2[v];
    }
    if (t < 256) ((uint4*)w1p)[t] = ((const uint4*)w1p_g)[t];
    if (t < 64)  ((uint4*)b3t)[t] = ((const uint4*)b3t_g)[t];
    __syncthreads();

    const int wid = t >> 6, lane = t & 63;
    const int l31 = lane & 31, lg2 = lane >> 5;
    char* sw = (char*)slab[wid];
    const int swz = (l31 & 7) << 4;

    // ---- loop-invariant register fragments ----
    s16x8 w1pf[4];
#pragma unroll
    for (int n = 0; n < 4; ++n)
        w1pf[n] = *(const s16x8*)((const char*)w1p + ((n * 32 + l31) << 5) + lg2 * 16);
    s16x8 b3f = *(const s16x8*)((const char*)b3t + (l31 << 5) + lg2 * 16);
    f32x16 b2f0, b2f1;
#pragma unroll
    for (int r = 0; r < 16; ++r) {
        const int row = (r & 3) + 8 * (r >> 2) + 4 * lg2;
        b2f0[r] = b2[row];
        b2f1[r] = b2[32 + row];
    }

    for (int chunk = blockIdx.x * 8 + wid; chunk < NCHUNK; chunk += FUSED_GRID * 8) {
        const int e = chunk * 32 + l31;
        const int sn = src[e];
        const f32x4* __restrict__ xp = (const f32x4*)(x + (size_t)sn * 16);
        f32x4 x0 = xp[0], x1 = xp[1], x2 = xp[2], x3 = xp[3];
        const float ea0 = ea[e * 3], ea1 = ea[e * 3 + 1], ea2 = ea[e * 3 + 2];

        // ---- L1: 4 MFMAs, pack D into L2 B-fragments ----
        s16x8 eb = (s16x8){0, 0, 0, 0, 0, 0, 0, 0};
        if (lg2 == 0) {
            eb[0] = (short)f2bf(ea0); eb[1] = (short)f2bf(ea1);
            eb[2] = (short)f2bf(ea2); eb[3] = (short)0x3F80;  // 1.0
        }
        s16x8 hb[8];
#pragma unroll
        for (int n = 0; n < 4; ++n) {
            f32x16 d = {0.f};
            d = __builtin_amdgcn_mfma_f32_32x32x16_bf16(w1pf[n], eb, d, 0, 0, 0);
#pragma unroll
            for (int s = 0; s < 2; ++s)
#pragma unroll
                for (int j = 0; j < 8; ++j)
                    hb[2 * n + s][j] = (short)f2bf(fmaxf(d[(j & 3) + 4 * (j >> 2) + 8 * s], 0.f));
        }

        // ---- L2: h2 = relu(w2t @ h1 + b2), 16 MFMAs; D -> slab ----
        asm volatile("s_waitcnt lgkmcnt(0)" ::: "memory");  // prior iter slab reads done
#pragma unroll
        for (int nblk = 0; nblk < 2; ++nblk) {
            f32x16 a2 = nblk ? b2f1 : b2f0;
            const char* __restrict__ w2row = (const char*)w2t + ((nblk * 32 + l31) << 8);
#pragma unroll
            for (int ks = 0; ks < 8; ++ks) {
                s16x8 a = *(const s16x8*)(w2row + ((ks * 32 + lg2 * 16) ^ swz));
                a2 = __builtin_amdgcn_mfma_f32_32x32x16_bf16(a, hb[ks], a2, 0, 0, 0);
            }
#pragma unroll
            for (int rh = 0; rh < 4; ++rh) {
                const int kb = nblk * 64 + rh * 16 + lg2 * 8;
                *(uint2*)(sw + l31 * 128 + (kb ^ swz)) =
                    pack_bf4(fmaxf(a2[rh * 4], 0.f), fmaxf(a2[rh * 4 + 1], 0.f),
                             fmaxf(a2[rh * 4 + 2], 0.f), fmaxf(a2[rh * 4 + 3], 0.f));
            }
        }
        asm volatile("s_waitcnt lgkmcnt(0)" ::: "memory");

        // ---- w3 B-fragments from slab ----
        s16x8 wb[4];
#pragma unroll
        for (int ks = 0; ks < 4; ++ks)
            wb[ks] = *(const s16x8*)(sw + l31 * 128 + ((ks * 32 + lg2 * 16) ^ swz));

        // ---- seed: p = mfma(b3t, x_bf16) ----
        s16x8 xbf;
        {
            f32x4 a0 = lg2 ? x2 : x0, a1 = lg2 ? x3 : x1;
#pragma unroll
            for (int i = 0; i < 4; ++i) {
                xbf[i] = (short)f2bf(a0[i]);
                xbf[i + 4] = (short)f2bf(a1[i]);
            }
        }
        f32x16 p = {0.f};
        p = __builtin_amdgcn_mfma_f32_32x32x16_bf16(b3f, xbf, p, 0, 0, 0);

        // ---- w3 GEMM + x-contraction (i = nblk, wave-uniform) ----
#pragma unroll
        for (int nblk = 0; nblk < 16; ++nblk) {
            const char* __restrict__ arow = (const char*)w3t + ((nblk * 32 + l31) << 7);
            f32x16 d = {0.f};
#pragma unroll
            for (int ks = 0; ks < 4; ++ks) {
                s16x8 a = *(const s16x8*)(arow + ((ks * 32 + lg2 * 16) ^ swz));
                d = __builtin_amdgcn_mfma_f32_32x32x16_bf16(a, wb[ks], d, 0, 0, 0);
            }
            const float xs = (nblk < 4 ? x0 : nblk < 8 ? x1 : nblk < 12 ? x2 : x3)[nblk & 3];
#pragma unroll
            for (int r = 0; r < 16; ++r) p[r] = fmaf(xs, d[r], p[r]);
        }

        // ---- msg via slab transpose ----
        asm volatile("s_waitcnt lgkmcnt(0)" ::: "memory");  // wb reads retired
#pragma unroll
        for (int rh = 0; rh < 4; ++rh) {
            const int ob = rh * 16 + lg2 * 8;
            *(uint2*)(sw + l31 * 64 + (ob ^ ((l31 & 7) << 3))) =
                pack_bf4(p[rh * 4], p[rh * 4 + 1], p[rh * 4 + 2], p[rh * 4 + 3]);
        }
        asm volatile("s_waitcnt lgkmcnt(0)" ::: "memory");
#pragma unroll
        for (int q = 0; q < 2; ++q) {
            const int er = (lane >> 2) + q * 16;
            const int off = (lane & 3) * 16;
            const int s8 = (er & 7) << 3;
            uint2 a = *(const uint2*)(sw + er * 64 + (off ^ s8));
            uint2 b = *(const uint2*)(sw + er * 64 + ((off + 8) ^ s8));
            *(uint4*)((char*)msg + (size_t)chunk * 2048 + q * 1024 + lane * 16) =
                make_uint4(a.x, a.y, b.x, b.y);
        }
    }
}

// ---------------- aggregate msg by dst (CSR gather) + root transform ----------------
__global__ __launch_bounds__(256) void k_agg(
    const unsigned short* __restrict__ msg, const int* __restrict__ rowptr,
    const int* __restrict__ eid, const float* __restrict__ x,
    const float* __restrict__ rw, const float* __restrict__ cb, float* __restrict__ h1)
{
    const int gid = blockIdx.x * 256 + threadIdx.x;
    const int n = (gid >> 6) * 2 + ((gid & 63) >> 5);
    if (n >= NN) return;
    const int o = gid & 31;
    const int r0 = rowptr[n], r1 = rowptr[n + 1];
    float acc = 0.f;
    for (int j = r0; j < r1; ++j)
        acc += bf2f(msg[(size_t)eid[j] * 32 + o]);
    const float* __restrict__ xr = x + (size_t)n * 16;
    float root = cb[o];
#pragma unroll
    for (int i = 0; i < 16; ++i) root = fmaf(xr[i], rw[i * 32 + o], root);
    h1[(size_t)n * 32 + o] = fmaxf(acc + root, 0.f);
}

// ---------------- GAT: node transform + attention coefficients ----------------
template <int FI>
__global__ __launch_bounds__(256) void k_gat_h(
    const float* __restrict__ hin, const float* __restrict__ W,
    const float* __restrict__ av_s, const float* __restrict__ av_d,
    float* __restrict__ h, float* __restrict__ as_v, float* __restrict__ ad_v)
{
    const int n = blockIdx.x * 256 + threadIdx.x;
    if (n >= NN) return;
    float acc[64];
#pragma unroll
    for (int o = 0; o < 64; ++o) acc[o] = 0.f;
    const f32x4* __restrict__ hp = (const f32x4*)(hin + (size_t)n * FI);
#pragma unroll 2
    for (int i4 = 0; i4 < FI / 4; ++i4) {
        f32x4 xi = hp[i4];
#pragma unroll
        for (int c = 0; c < 4; ++c) {
            const float xv = xi[c];
            const float* __restrict__ wr = W + (i4 * 4 + c) * 64;
#pragma unroll
            for (int o = 0; o < 64; ++o) acc[o] = fmaf(xv, wr[o], acc[o]);
        }
    }
    float s = 0.f, d = 0.f;
#pragma unroll
    for (int o = 0; o < 64; ++o) {
        h[(size_t)n * 64 + o] = acc[o];
        s = fmaf(acc[o], av_s[o], s);
        d = fmaf(acc[o], av_d[o], d);
    }
    as_v[n] = s;
    ad_v[n] = d;
}

// ---------------- GAT: per-node softmax + weighted gather (one wave per node) ----------------
__global__ __launch_bounds__(256) void k_gat_node(
    const int* __restrict__ rowptr, const int* __restrict__ eid, const int* __restrict__ src,
    const float* __restrict__ h, const float* __restrict__ as_v, const float* __restrict__ ad_v,
    const float* __restrict__ b, float* __restrict__ out)
{
    const int n = (blockIdx.x * 256 + threadIdx.x) >> 6;
    if (n >= NN) return;
    const int lane = threadIdx.x & 63;
    const int r0 = rowptr[n], r1 = rowptr[n + 1];
    const float adn = ad_v[n];
    const float l_self = lrelu(as_v[n] + adn);
    float m = l_self;
    for (int j = r0 + lane; j < r1; j += 64)
        m = fmaxf(m, lrelu(as_v[src[eid[j]]] + adn));
#pragma unroll
    for (int off = 32; off; off >>= 1) m = fmaxf(m, __shfl_xor(m, off));
    float s = 0.f;
    for (int j = r0 + lane; j < r1; j += 64)
        s += expf(lrelu(as_v[src[eid[j]]] + adn) - m);
#pragma unroll
    for (int off = 32; off; off >>= 1) s += __shfl_xor(s, off);
    const float w_self = expf(l_self - m);
    s += w_self;
    float acc = w_self * h[(size_t)n * 64 + lane];
    for (int j = r0; j < r1; ++j) {
        const int sn = src[eid[j]];
        const float w = expf(lrelu(as_v[sn] + adn) - m);
        acc = fmaf(w, h[(size_t)sn * 64 + lane], acc);
    }
    out[(size_t)n * 64 + lane] = fmaxf(acc / s + b[lane], 0.f);
}

// ---------------- global mean pool ----------------
__global__ __launch_bounds__(256) void k_pool1(
    const float* __restrict__ h, const int* __restrict__ batch,
    float* __restrict__ gsum, float* __restrict__ gcnt)
{
    __shared__ float ls[NG * 64];
    __shared__ float lc[NG];
    for (int j = threadIdx.x; j < NG * 64; j += 256) ls[j] = 0.f;
    if (threadIdx.x < NG) lc[threadIdx.x] = 0.f;
    __syncthreads();
    const int base = blockIdx.x * 512;
    for (int idx = threadIdx.x; idx < 512 * 64; idx += 256) {
        const int nl = idx >> 6, f = idx & 63;
        const int n = base + nl;
        if (n < NN) {
            const int g = batch[n];
            atomicAdd(&ls[g * 64 + f], h[(size_t)n * 64 + f]);
            if (f == 0) atomicAdd(&lc[g], 1.f);
        }
    }
    __syncthreads();
    for (int j = threadIdx.x; j < NG * 64; j += 256) atomicAdd(&gsum[j], ls[j]);
    if (threadIdx.x < NG) atomicAdd(&gcnt[threadIdx.x], lc[threadIdx.x]);
}

__global__ __launch_bounds__(256) void k_pool2(
    const float* __restrict__ gsum, const float* __restrict__ gcnt, float* __restrict__ out)
{
    const int idx = blockIdx.x * 256 + threadIdx.x;
    if (idx >= NG * 64) return;
    out[idx] = gsum[idx] / fmaxf(gcnt[idx >> 6], 1.f);
}

extern "C" void kernel_launch(void* const* d_in, const int* in_sizes, int n_in,
                              void* d_out, int out_size, void* d_ws, size_t ws_size,
                              hipStream_t stream)
{
    const float* x     = (const float*)d_in[0];
    const float* ea    = (const float*)d_in[1];
    const int*   ei    = (const int*)d_in[2];
    const int*   batch = (const int*)d_in[3];
    const float* w1 = (const float*)d_in[4];   const float* b1 = (const float*)d_in[5];
    const float* w2 = (const float*)d_in[6];   const float* b2 = (const float*)d_in[7];
    const float* w3 = (const float*)d_in[8];   const float* b3 = (const float*)d_in[9];
    const float* rw = (const float*)d_in[10];  const float* cb = (const float*)d_in[11];
    const float* g1w  = (const float*)d_in[12]; const float* g1as = (const float*)d_in[13];
    const float* g1ad = (const float*)d_in[14]; const float* g1b  = (const float*)d_in[15];
    const float* g2w  = (const float*)d_in[16]; const float* g2as = (const float*)d_in[17];
    const float* g2ad = (const float*)d_in[18]; const float* g2b  = (const float*)d_in[19];
    const int* src = ei;
    const int* dst = ei + NE;
    float* out = (float*)d_out;
    (void)in_sizes; (void)n_in; (void)out_size; (void)ws_size;

    char* ws = (char*)d_ws;
    size_t off = 0;
    auto alloc = [&](size_t bytes) -> char* {
        char* p = ws + off;
        off += (bytes + 255) & ~(size_t)255;
        return p;
    };
    int*  deg    = (int*)alloc((size_t)NN * 4);
    int*  cursor = (int*)alloc((size_t)NN * 4);
    int*  rowptr = (int*)alloc((size_t)(NN + 1) * 4);
    int*  bsum   = (int*)alloc((size_t)NSB * 4);
    int*  eid    = (int*)alloc((size_t)NE * 4);
    unsigned short* w3t_g = (unsigned short*)alloc((size_t)64 * 512 * 2);
    unsigned short* w2t_g = (unsigned short*)alloc((size_t)64 * 128 * 2);
    unsigned short* w1p_g = (unsigned short*)alloc((size_t)128 * 16 * 2);
    unsigned short* b3t_g = (unsigned short*)alloc((size_t)512 * 2);
    unsigned short* msg   = (unsigned short*)alloc((size_t)NE * 32 * 2);  // 25.6 MB
    float* h1   = (float*)alloc((size_t)NN * 32 * 4);
    float* hB   = (float*)alloc((size_t)NN * 64 * 4);
    float* hC   = (float*)alloc((size_t)NN * 64 * 4);
    float* hD   = (float*)alloc((size_t)NN * 64 * 4);
    float* as_v = (float*)alloc((size_t)NN * 4);
    float* ad_v = (float*)alloc((size_t)NN * 4);
    float* gsum = (float*)alloc((size_t)NG * 64 * 4);
    float* gcnt = (float*)alloc((size_t)NG * 4);

    hipMemsetAsync(deg, 0, (size_t)NN * 4, stream);
    hipMemsetAsync(gsum, 0, (size_t)NG * 64 * 4, stream);
    hipMemsetAsync(gcnt, 0, (size_t)NG * 4, stream);

    // CSR build (parallel hierarchical scan)
    k_hist<<<(NE + 255) / 256, 256, 0, stream>>>(dst, deg);
    k_bsum<<<NSB, 256, 0, stream>>>(deg, bsum);
    k_scan2<<<NSB, 256, 0, stream>>>(deg, bsum, rowptr, cursor);
    k_perm<<<(NE + 255) / 256, 256, 0, stream>>>(dst, cursor, eid);

    // NNConv (fused, all-MFMA)
    k_wprep<<<(64 * 512 + 255) / 256, 256, 0, stream>>>(w3, w2, w1, b1, b3,
                                                        w3t_g, w2t_g, w1p_g, b3t_g);
    k_fused<<<FUSED_GRID, 512, 0, stream>>>(ea, w1p_g, w2t_g, b2, w3t_g, b3t_g, src, x, msg);
    k_agg<<<(NN / 2 * 64 + 255) / 256 + 1, 256, 0, stream>>>(msg, rowptr, eid, x, rw, cb, h1);

    // GAT layer 1
    k_gat_h<32><<<(NN + 255) / 256, 256, 0, stream>>>(h1, g1w, g1as, g1ad, hB, as_v, ad_v);
    k_gat_node<<<(NN * 64 + 255) / 256, 256, 0, stream>>>(rowptr, eid, src, hB, as_v, ad_v, g1b, hC);

    // GAT layer 2
    k_gat_h<64><<<(NN + 255) / 256, 256, 0, stream>>>(hC, g2w, g2as, g2ad, hB, as_v, ad_v);
    k_gat_node<<<(NN * 64 + 255) / 256, 256, 0, stream>>>(rowptr, eid, src, hB, as_v, ad_v, g2b, hD);

    // pool
    k_pool1<<<(NN + 511) / 512, 256, 0, stream>>>(hD, batch, gsum, gcnt);
    k_pool2<<<(NG * 64 + 255) / 256, 256, 0, stream>>>(gsum, gcnt, out);
}

// Round 10
// 359.971 us; speedup vs baseline: 2.8655x; 1.1283x over previous
//
#include <hip/hip_runtime.h>

#define NN 50000
#define NE 400000
#define NG 32
#define SLOPE 0.2f
#define NSB ((NN + 255) / 256)   // 196 scan blocks

typedef __attribute__((ext_vector_type(4))) float f32x4;
typedef __attribute__((ext_vector_type(16))) float f32x16;
typedef __attribute__((ext_vector_type(8))) short s16x8;

__device__ __forceinline__ float lrelu(float v) { return v > 0.f ? v : SLOPE * v; }
__device__ __forceinline__ unsigned short f2bf(float f) {
    union { float f; unsigned u; } c; c.f = f;
    unsigned r = c.u + 0x7fffu + ((c.u >> 16) & 1u);
    return (unsigned short)(r >> 16);
}
__device__ __forceinline__ float bf2f(unsigned short b) {
    union { unsigned u; float f; } c; c.u = ((unsigned)b) << 16; return c.f;
}
__device__ __forceinline__ unsigned pack2(float a, float b) {
    return (unsigned)f2bf(a) | ((unsigned)f2bf(b) << 16);
}
__device__ __forceinline__ uint2 pack_bf4(float a, float b, float c, float d) {
    uint2 u;
    u.x = pack2(a, b);
    u.y = pack2(c, d);
    return u;
}

// ---------------- CSR build ----------------
__global__ __launch_bounds__(256) void k_hist(const int* __restrict__ dst, int* __restrict__ deg) {
    int e = blockIdx.x * 256 + threadIdx.x;
    if (e < NE) atomicAdd(&deg[dst[e]], 1);
}

__global__ __launch_bounds__(256) void k_bsum(const int* __restrict__ deg, int* __restrict__ bsum) {
    __shared__ int ls[256];
    const int t = threadIdx.x;
    const int idx = blockIdx.x * 256 + t;
    ls[t] = (idx < NN) ? deg[idx] : 0;
    __syncthreads();
#pragma unroll
    for (int off = 128; off; off >>= 1) {
        if (t < off) ls[t] += ls[t + off];
        __syncthreads();
    }
    if (t == 0) bsum[blockIdx.x] = ls[0];
}

__global__ __launch_bounds__(256) void k_scan2(const int* __restrict__ deg,
                                               const int* __restrict__ bsum,
                                               int* __restrict__ rowptr, int* __restrict__ cursor) {
    __shared__ int lb[256];
    __shared__ int ls[256];
    const int t = threadIdx.x, b = blockIdx.x;
    lb[t] = (t < NSB && t < b) ? bsum[t] : 0;
    const int idx = b * 256 + t;
    const int v = (idx < NN) ? deg[idx] : 0;
    ls[t] = v;
    __syncthreads();
#pragma unroll
    for (int off = 128; off; off >>= 1) {
        if (t < off) lb[t] += lb[t + off];
        __syncthreads();
    }
#pragma unroll
    for (int off = 1; off < 256; off <<= 1) {
        int u = (t >= off) ? ls[t - off] : 0;
        __syncthreads();
        ls[t] += u;
        __syncthreads();
    }
    if (idx < NN) {
        const int run = lb[0] + ls[t] - v;
        rowptr[idx] = run;
        cursor[idx] = run;
    }
    if (b == 0 && t == 0) rowptr[NN] = NE;
}

// also emits srcp = src in CSR order (kills one indirection in GAT)
__global__ __launch_bounds__(256) void k_perm(const int* __restrict__ dst, const int* __restrict__ src,
                                              int* __restrict__ cursor, int* __restrict__ eid,
                                              int* __restrict__ srcp) {
    int e = blockIdx.x * 256 + threadIdx.x;
    if (e < NE) {
        int p = atomicAdd(&cursor[dst[e]], 1);
        eid[p] = e;
        srcp[p] = src[e];
    }
}

// ---------------- one-time weight prep (unchanged from R9) ----------------
__global__ __launch_bounds__(256) void k_wprep(const float* __restrict__ w3,
                                               const float* __restrict__ w2,
                                               const float* __restrict__ w1,
                                               const float* __restrict__ b1,
                                               const float* __restrict__ b3,
                                               unsigned short* __restrict__ w3t_g,
                                               unsigned short* __restrict__ w2t_g,
                                               unsigned short* __restrict__ w1p_g,
                                               unsigned short* __restrict__ b3t_g) {
    const int v = blockIdx.x * 256 + threadIdx.x;
    if (v < 64 * 512) {
        const int k = v >> 9, n = v & 511;
        const int byte = (n << 7) | ((k << 1) ^ ((n & 7) << 4));
        *(unsigned short*)((char*)w3t_g + byte) = f2bf(w3[v]);
    }
    if (v < 64 * 128) {
        const int o = v & 63, slot = v >> 6;
        const int ks = slot >> 4, lg2 = (slot >> 3) & 1, j = slot & 7;
        const int kp = (ks >> 1) * 32 + (j & 3) + 8 * (j >> 2) + 16 * (ks & 1) + 4 * lg2;
        const int byte = (o << 8) | ((slot << 1) ^ ((o & 7) << 4));
        *(unsigned short*)((char*)w2t_g + byte) = f2bf(w2[kp * 64 + o]);
    }
    if (v < 128 * 16) {
        const int j = v >> 4, k = v & 15;
        float val = (k < 3) ? w1[k * 128 + j] : (k == 3 ? b1[j] : 0.f);
        w1p_g[v] = f2bf(val);
    }
    if (v < 512) {
        const int i = v >> 5, o = v & 31;
        b3t_g[o * 16 + i] = f2bf(b3[v]);
    }
}

// ---------------- fused NNConv (unchanged from R9) ----------------
#define FUSED_GRID 256
#define NCHUNK (NE / 32)
__global__ __launch_bounds__(512, 1) void k_fused(
    const float* __restrict__ ea,
    const unsigned short* __restrict__ w1p_g,
    const unsigned short* __restrict__ w2t_g, const float* __restrict__ b2,
    const unsigned short* __restrict__ w3t_g, const unsigned short* __restrict__ b3t_g,
    const int* __restrict__ src, const float* __restrict__ x,
    unsigned short* __restrict__ msg)
{
    __shared__ __align__(16) unsigned short w3t[512 * 64];
    __shared__ __align__(16) unsigned short w2t[64 * 128];
    __shared__ __align__(16) unsigned short w1p[128 * 16];
    __shared__ __align__(16) unsigned short b3t[512];
    __shared__ __align__(16) unsigned slab[8][1024];

    const int t = threadIdx.x;
    {
        const uint4* g = (const uint4*)w3t_g;
        uint4* l = (uint4*)w3t;
        for (int v = t; v < 4096; v += 512) l[v] = g[v];
        const uint4* g2 = (const uint4*)w2t_g;
        uint4* l2 = (uint4*)w2t;
        for (int v = t; v < 1024; v += 512) l2[v] = g2[v];
    }
    if (t < 256) ((uint4*)w1p)[t] = ((const uint4*)w1p_g)[t];
    if (t < 64)  ((uint4*)b3t)[t] = ((const uint4*)b3t_g)[t];
    __syncthreads();

    const int wid = t >> 6, lane = t & 63;
    const int l31 = lane & 31, lg2 = lane >> 5;
    char* sw = (char*)slab[wid];
    const int swz = (l31 & 7) << 4;

    s16x8 w1pf[4];
#pragma unroll
    for (int n = 0; n < 4; ++n)
        w1pf[n] = *(const s16x8*)((const char*)w1p + ((n * 32 + l31) << 5) + lg2 * 16);
    s16x8 b3f = *(const s16x8*)((const char*)b3t + (l31 << 5) + lg2 * 16);
    f32x16 b2f0, b2f1;
#pragma unroll
    for (int r = 0; r < 16; ++r) {
        const int row = (r & 3) + 8 * (r >> 2) + 4 * lg2;
        b2f0[r] = b2[row];
        b2f1[r] = b2[32 + row];
    }

    for (int chunk = blockIdx.x * 8 + wid; chunk < NCHUNK; chunk += FUSED_GRID * 8) {
        const int e = chunk * 32 + l31;
        const int sn = src[e];
        const f32x4* __restrict__ xp = (const f32x4*)(x + (size_t)sn * 16);
        f32x4 x0 = xp[0], x1 = xp[1], x2 = xp[2], x3 = xp[3];
        const float ea0 = ea[e * 3], ea1 = ea[e * 3 + 1], ea2 = ea[e * 3 + 2];

        s16x8 eb = (s16x8){0, 0, 0, 0, 0, 0, 0, 0};
        if (lg2 == 0) {
            eb[0] = (short)f2bf(ea0); eb[1] = (short)f2bf(ea1);
            eb[2] = (short)f2bf(ea2); eb[3] = (short)0x3F80;
        }
        s16x8 hb[8];
#pragma unroll
        for (int n = 0; n < 4; ++n) {
            f32x16 d = {0.f};
            d = __builtin_amdgcn_mfma_f32_32x32x16_bf16(w1pf[n], eb, d, 0, 0, 0);
#pragma unroll
            for (int s = 0; s < 2; ++s)
#pragma unroll
                for (int j = 0; j < 8; ++j)
                    hb[2 * n + s][j] = (short)f2bf(fmaxf(d[(j & 3) + 4 * (j >> 2) + 8 * s], 0.f));
        }

        asm volatile("s_waitcnt lgkmcnt(0)" ::: "memory");
#pragma unroll
        for (int nblk = 0; nblk < 2; ++nblk) {
            f32x16 a2 = nblk ? b2f1 : b2f0;
            const char* __restrict__ w2row = (const char*)w2t + ((nblk * 32 + l31) << 8);
#pragma unroll
            for (int ks = 0; ks < 8; ++ks) {
                s16x8 a = *(const s16x8*)(w2row + ((ks * 32 + lg2 * 16) ^ swz));
                a2 = __builtin_amdgcn_mfma_f32_32x32x16_bf16(a, hb[ks], a2, 0, 0, 0);
            }
#pragma unroll
            for (int rh = 0; rh < 4; ++rh) {
                const int kb = nblk * 64 + rh * 16 + lg2 * 8;
                *(uint2*)(sw + l31 * 128 + (kb ^ swz)) =
                    pack_bf4(fmaxf(a2[rh * 4], 0.f), fmaxf(a2[rh * 4 + 1], 0.f),
                             fmaxf(a2[rh * 4 + 2], 0.f), fmaxf(a2[rh * 4 + 3], 0.f));
            }
        }
        asm volatile("s_waitcnt lgkmcnt(0)" ::: "memory");

        s16x8 wb[4];
#pragma unroll
        for (int ks = 0; ks < 4; ++ks)
            wb[ks] = *(const s16x8*)(sw + l31 * 128 + ((ks * 32 + lg2 * 16) ^ swz));

        s16x8 xbf;
        {
            f32x4 a0 = lg2 ? x2 : x0, a1 = lg2 ? x3 : x1;
#pragma unroll
            for (int i = 0; i < 4; ++i) {
                xbf[i] = (short)f2bf(a0[i]);
                xbf[i + 4] = (short)f2bf(a1[i]);
            }
        }
        f32x16 p = {0.f};
        p = __builtin_amdgcn_mfma_f32_32x32x16_bf16(b3f, xbf, p, 0, 0, 0);

#pragma unroll
        for (int nblk = 0; nblk < 16; ++nblk) {
            const char* __restrict__ arow = (const char*)w3t + ((nblk * 32 + l31) << 7);
            f32x16 d = {0.f};
#pragma unroll
            for (int ks = 0; ks < 4; ++ks) {
                s16x8 a = *(const s16x8*)(arow + ((ks * 32 + lg2 * 16) ^ swz));
                d = __builtin_amdgcn_mfma_f32_32x32x16_bf16(a, wb[ks], d, 0, 0, 0);
            }
            const float xs = (nblk < 4 ? x0 : nblk < 8 ? x1 : nblk < 12 ? x2 : x3)[nblk & 3];
#pragma unroll
            for (int r = 0; r < 16; ++r) p[r] = fmaf(xs, d[r], p[r]);
        }

        asm volatile("s_waitcnt lgkmcnt(0)" ::: "memory");
#pragma unroll
        for (int rh = 0; rh < 4; ++rh) {
            const int ob = rh * 16 + lg2 * 8;
            *(uint2*)(sw + l31 * 64 + (ob ^ ((l31 & 7) << 3))) =
                pack_bf4(p[rh * 4], p[rh * 4 + 1], p[rh * 4 + 2], p[rh * 4 + 3]);
        }
        asm volatile("s_waitcnt lgkmcnt(0)" ::: "memory");
#pragma unroll
        for (int q = 0; q < 2; ++q) {
            const int er = (lane >> 2) + q * 16;
            const int off = (lane & 3) * 16;
            const int s8 = (er & 7) << 3;
            uint2 a = *(const uint2*)(sw + er * 64 + (off ^ s8));
            uint2 b = *(const uint2*)(sw + er * 64 + ((off + 8) ^ s8));
            *(uint4*)((char*)msg + (size_t)chunk * 2048 + q * 1024 + lane * 16) =
                make_uint4(a.x, a.y, b.x, b.y);
        }
    }
}

// ---------------- aggregate msg by dst (CSR gather) + root transform ----------------
__global__ __launch_bounds__(256) void k_agg(
    const unsigned short* __restrict__ msg, const int* __restrict__ rowptr,
    const int* __restrict__ eid, const float* __restrict__ x,
    const float* __restrict__ rw, const float* __restrict__ cb, float* __restrict__ h1)
{
    const int gid = blockIdx.x * 256 + threadIdx.x;
    const int n = (gid >> 6) * 2 + ((gid & 63) >> 5);
    if (n >= NN) return;
    const int o = gid & 31;
    const int r0 = rowptr[n], r1 = rowptr[n + 1];
    float acc = 0.f;
    for (int j = r0; j < r1; ++j)
        acc += bf2f(msg[(size_t)eid[j] * 32 + o]);
    const float* __restrict__ xr = x + (size_t)n * 16;
    float root = cb[o];
#pragma unroll
    for (int i = 0; i < 16; ++i) root = fmaf(xr[i], rw[i * 32 + o], root);
    h1[(size_t)n * 32 + o] = fmaxf(acc + root, 0.f);
}

// ---------------- GAT: node transform (bf16 packed output) + attention coefficients ----------
template <int FI, bool BFIN>
__global__ __launch_bounds__(256) void k_gat_h(
    const void* __restrict__ hin, const float* __restrict__ W,
    const float* __restrict__ av_s, const float* __restrict__ av_d,
    unsigned* __restrict__ hbf, float* __restrict__ as_v, float* __restrict__ ad_v)
{
    const int n = blockIdx.x * 256 + threadIdx.x;
    if (n >= NN) return;
    float acc[64];
#pragma unroll
    for (int o = 0; o < 64; ++o) acc[o] = 0.f;

    float xv[FI];
    if constexpr (BFIN) {
        const uint4* __restrict__ hp = (const uint4*)((const unsigned*)hin + (size_t)n * (FI / 2));
#pragma unroll
        for (int q = 0; q < FI / 8; ++q) {
            uint4 v = hp[q];
            const unsigned w4[4] = {v.x, v.y, v.z, v.w};
#pragma unroll
            for (int c = 0; c < 4; ++c) {
                xv[q * 8 + 2 * c]     = bf2f((unsigned short)(w4[c] & 0xffff));
                xv[q * 8 + 2 * c + 1] = bf2f((unsigned short)(w4[c] >> 16));
            }
        }
    } else {
        const f32x4* __restrict__ hp = (const f32x4*)((const float*)hin + (size_t)n * FI);
#pragma unroll
        for (int q = 0; q < FI / 4; ++q) {
            f32x4 v = hp[q];
#pragma unroll
            for (int c = 0; c < 4; ++c) xv[q * 4 + c] = v[c];
        }
    }
#pragma unroll 2
    for (int i = 0; i < FI; ++i) {
        const float xi = xv[i];
        const float* __restrict__ wr = W + i * 64;
#pragma unroll
        for (int o = 0; o < 64; ++o) acc[o] = fmaf(xi, wr[o], acc[o]);
    }
    float s = 0.f, d = 0.f;
#pragma unroll
    for (int o = 0; o < 64; ++o) {
        s = fmaf(acc[o], av_s[o], s);
        d = fmaf(acc[o], av_d[o], d);
    }
    as_v[n] = s;
    ad_v[n] = d;
    uint4* __restrict__ op = (uint4*)(hbf + (size_t)n * 32);
#pragma unroll
    for (int q = 0; q < 8; ++q)
        op[q] = make_uint4(pack2(acc[8 * q], acc[8 * q + 1]), pack2(acc[8 * q + 2], acc[8 * q + 3]),
                           pack2(acc[8 * q + 4], acc[8 * q + 5]), pack2(acc[8 * q + 6], acc[8 * q + 7]));
}

// asp[j] = as_v[srcp[j]] : one random-gather pass; all softmax passes then stream
__global__ __launch_bounds__(256) void k_easrc(const int* __restrict__ srcp,
                                               const float* __restrict__ as_v,
                                               float* __restrict__ asp) {
    int j = blockIdx.x * 256 + threadIdx.x;
    if (j < NE) asp[j] = as_v[srcp[j]];
}

// ---------------- GAT: per-node softmax + weighted gather (bf16 rows, 2-edge ILP) -----------
__global__ __launch_bounds__(256) void k_gat_node(
    const int* __restrict__ rowptr, const int* __restrict__ srcp, const float* __restrict__ asp,
    const unsigned* __restrict__ hbf, const float* __restrict__ as_v, const float* __restrict__ ad_v,
    const float* __restrict__ b, unsigned* __restrict__ outbf)
{
    const int n = (blockIdx.x * 256 + threadIdx.x) >> 6;
    if (n >= NN) return;
    const int lane = threadIdx.x & 63;
    const int l31 = lane & 31, g = lane >> 5;
    const int r0 = rowptr[n], r1 = rowptr[n + 1];
    const float adn = ad_v[n];
    const float l_self = lrelu(as_v[n] + adn);
    // pass 1: max (linear asp reads)
    float m = l_self;
    for (int j = r0 + lane; j < r1; j += 64)
        m = fmaxf(m, lrelu(asp[j] + adn));
#pragma unroll
    for (int off = 32; off; off >>= 1) m = fmaxf(m, __shfl_xor(m, off));
    // pass 2: denom (asp now L1-hot)
    float s = 0.f;
    for (int j = r0 + lane; j < r1; j += 64)
        s += expf(lrelu(asp[j] + adn) - m);
#pragma unroll
    for (int off = 32; off; off >>= 1) s += __shfl_xor(s, off);
    const float w_self = expf(l_self - m);
    s += w_self;
    // pass 3: features — half-waves alternate edges, lane = 2 packed features
    float a0 = 0.f, a1 = 0.f;
    if (g == 0) {
        const unsigned hv = hbf[(size_t)n * 32 + l31];
        a0 = w_self * bf2f((unsigned short)(hv & 0xffff));
        a1 = w_self * bf2f((unsigned short)(hv >> 16));
    }
    for (int j = r0 + g; j < r1; j += 2) {
        const int sn = srcp[j];
        const float w = expf(lrelu(asp[j] + adn) - m);
        const unsigned hv = hbf[(size_t)sn * 32 + l31];
        a0 = fmaf(w, bf2f((unsigned short)(hv & 0xffff)), a0);
        a1 = fmaf(w, bf2f((unsigned short)(hv >> 16)), a1);
    }
    a0 += __shfl_xor(a0, 32);
    a1 += __shfl_xor(a1, 32);
    if (g == 0) {
        const float v0 = fmaxf(a0 / s + b[2 * l31], 0.f);
        const float v1 = fmaxf(a1 / s + b[2 * l31 + 1], 0.f);
        outbf[(size_t)n * 32 + l31] = pack2(v0, v1);
    }
}

// ---------------- global mean pool (bf16 input) ----------------
__global__ __launch_bounds__(256) void k_pool1(
    const unsigned* __restrict__ hbf, const int* __restrict__ batch,
    float* __restrict__ gsum, float* __restrict__ gcnt)
{
    __shared__ float ls[NG * 64];
    __shared__ float lc[NG];
    for (int j = threadIdx.x; j < NG * 64; j += 256) ls[j] = 0.f;
    if (threadIdx.x < NG) lc[threadIdx.x] = 0.f;
    __syncthreads();
    const int base = blockIdx.x * 512;
    for (int idx = threadIdx.x; idx < 512 * 32; idx += 256) {
        const int nl = idx >> 5, f2 = idx & 31;
        const int n = base + nl;
        if (n < NN) {
            const int g = batch[n];
            const unsigned hv = hbf[(size_t)n * 32 + f2];
            atomicAdd(&ls[g * 64 + 2 * f2], bf2f((unsigned short)(hv & 0xffff)));
            atomicAdd(&ls[g * 64 + 2 * f2 + 1], bf2f((unsigned short)(hv >> 16)));
            if (f2 == 0) atomicAdd(&lc[g], 1.f);
        }
    }
    __syncthreads();
    for (int j = threadIdx.x; j < NG * 64; j += 256) atomicAdd(&gsum[j], ls[j]);
    if (threadIdx.x < NG) atomicAdd(&gcnt[threadIdx.x], lc[threadIdx.x]);
}

__global__ __launch_bounds__(256) void k_pool2(
    const float* __restrict__ gsum, const float* __restrict__ gcnt, float* __restrict__ out)
{
    const int idx = blockIdx.x * 256 + threadIdx.x;
    if (idx >= NG * 64) return;
    out[idx] = gsum[idx] / fmaxf(gcnt[idx >> 6], 1.f);
}

extern "C" void kernel_launch(void* const* d_in, const int* in_sizes, int n_in,
                              void* d_out, int out_size, void* d_ws, size_t ws_size,
                              hipStream_t stream)
{
    const float* x     = (const float*)d_in[0];
    const float* ea    = (const float*)d_in[1];
    const int*   ei    = (const int*)d_in[2];
    const int*   batch = (const int*)d_in[3];
    const float* w1 = (const float*)d_in[4];   const float* b1 = (const float*)d_in[5];
    const float* w2 = (const float*)d_in[6];   const float* b2 = (const float*)d_in[7];
    const float* w3 = (const float*)d_in[8];   const float* b3 = (const float*)d_in[9];
    const float* rw = (const float*)d_in[10];  const float* cb = (const float*)d_in[11];
    const float* g1w  = (const float*)d_in[12]; const float* g1as = (const float*)d_in[13];
    const float* g1ad = (const float*)d_in[14]; const float* g1b  = (const float*)d_in[15];
    const float* g2w  = (const float*)d_in[16]; const float* g2as = (const float*)d_in[17];
    const float* g2ad = (const float*)d_in[18]; const float* g2b  = (const float*)d_in[19];
    const int* src = ei;
    const int* dst = ei + NE;
    float* out = (float*)d_out;
    (void)in_sizes; (void)n_in; (void)out_size; (void)ws_size;

    char* ws = (char*)d_ws;
    size_t off = 0;
    auto alloc = [&](size_t bytes) -> char* {
        char* p = ws + off;
        off += (bytes + 255) & ~(size_t)255;
        return p;
    };
    int*  deg    = (int*)alloc((size_t)NN * 4);
    int*  cursor = (int*)alloc((size_t)NN * 4);
    int*  rowptr = (int*)alloc((size_t)(NN + 1) * 4);
    int*  bsum   = (int*)alloc((size_t)NSB * 4);
    int*  eid    = (int*)alloc((size_t)NE * 4);
    int*  srcp   = (int*)alloc((size_t)NE * 4);
    float* asp   = (float*)alloc((size_t)NE * 4);
    unsigned short* w3t_g = (unsigned short*)alloc((size_t)64 * 512 * 2);
    unsigned short* w2t_g = (unsigned short*)alloc((size_t)64 * 128 * 2);
    unsigned short* w1p_g = (unsigned short*)alloc((size_t)128 * 16 * 2);
    unsigned short* b3t_g = (unsigned short*)alloc((size_t)512 * 2);
    unsigned short* msg   = (unsigned short*)alloc((size_t)NE * 32 * 2);  // 25.6 MB
    float* h1    = (float*)alloc((size_t)NN * 32 * 4);
    unsigned* hT = (unsigned*)alloc((size_t)NN * 32 * 4);   // transformed h, bf16 packed
    unsigned* hC = (unsigned*)alloc((size_t)NN * 32 * 4);   // GAT1 output, bf16 packed
    unsigned* hD = (unsigned*)alloc((size_t)NN * 32 * 4);   // GAT2 output, bf16 packed
    float* as_v = (float*)alloc((size_t)NN * 4);
    float* ad_v = (float*)alloc((size_t)NN * 4);
    float* gsum = (float*)alloc((size_t)NG * 64 * 4);
    float* gcnt = (float*)alloc((size_t)NG * 4);

    hipMemsetAsync(deg, 0, (size_t)NN * 4, stream);
    hipMemsetAsync(gsum, 0, (size_t)NG * 64 * 4, stream);
    hipMemsetAsync(gcnt, 0, (size_t)NG * 4, stream);

    // CSR build
    k_hist<<<(NE + 255) / 256, 256, 0, stream>>>(dst, deg);
    k_bsum<<<NSB, 256, 0, stream>>>(deg, bsum);
    k_scan2<<<NSB, 256, 0, stream>>>(deg, bsum, rowptr, cursor);
    k_perm<<<(NE + 255) / 256, 256, 0, stream>>>(dst, src, cursor, eid, srcp);

    // NNConv (fused, all-MFMA)
    k_wprep<<<(64 * 512 + 255) / 256, 256, 0, stream>>>(w3, w2, w1, b1, b3,
                                                        w3t_g, w2t_g, w1p_g, b3t_g);
    k_fused<<<FUSED_GRID, 512, 0, stream>>>(ea, w1p_g, w2t_g, b2, w3t_g, b3t_g, src, x, msg);
    k_agg<<<(NN / 2 * 64 + 255) / 256 + 1, 256, 0, stream>>>(msg, rowptr, eid, x, rw, cb, h1);

    // GAT layer 1
    k_gat_h<32, false><<<(NN + 255) / 256, 256, 0, stream>>>(h1, g1w, g1as, g1ad, hT, as_v, ad_v);
    k_easrc<<<(NE + 255) / 256, 256, 0, stream>>>(srcp, as_v, asp);
    k_gat_node<<<(NN * 64 + 255) / 256, 256, 0, stream>>>(rowptr, srcp, asp, hT, as_v, ad_v, g1b, hC);

    // GAT layer 2
    k_gat_h<64, true><<<(NN + 255) / 256, 256, 0, stream>>>(hC, g2w, g2as, g2ad, hT, as_v, ad_v);
    k_easrc<<<(NE + 255) / 256, 256, 0, stream>>>(srcp, as_v, asp);
    k_gat_node<<<(NN * 64 + 255) / 256, 256, 0, stream>>>(rowptr, srcp, asp, hT, as_v, ad_v, g2b, hD);

    // pool
    k_pool1<<<(NN + 511) / 512, 256, 0, stream>>>(hD, batch, gsum, gcnt);
    k_pool2<<<(NG * 64 + 255) / 256, 256, 0, stream>>>(gsum, gcnt, out);
}

// Round 11
// 334.402 us; speedup vs baseline: 3.0846x; 1.0765x over previous
//
#include <hip/hip_runtime.h>

#define NN 50000
#define NE 400000
#define NG 32
#define SLOPE 0.2f
#define NSB ((NN + 255) / 256)   // 196 scan blocks

typedef __attribute__((ext_vector_type(4))) float f32x4;
typedef __attribute__((ext_vector_type(16))) float f32x16;
typedef __attribute__((ext_vector_type(8))) short s16x8;

__device__ __forceinline__ float lrelu(float v) { return v > 0.f ? v : SLOPE * v; }
__device__ __forceinline__ unsigned short f2bf(float f) {
    union { float f; unsigned u; } c; c.f = f;
    unsigned r = c.u + 0x7fffu + ((c.u >> 16) & 1u);
    return (unsigned short)(r >> 16);
}
__device__ __forceinline__ float bf2f(unsigned short b) {
    union { unsigned u; float f; } c; c.u = ((unsigned)b) << 16; return c.f;
}
__device__ __forceinline__ unsigned pack2(float a, float b) {
    return (unsigned)f2bf(a) | ((unsigned)f2bf(b) << 16);
}
__device__ __forceinline__ uint2 pack_bf4(float a, float b, float c, float d) {
    uint2 u;
    u.x = pack2(a, b);
    u.y = pack2(c, d);
    return u;
}

// ---------------- CSR build ----------------
__global__ __launch_bounds__(256) void k_hist(const int* __restrict__ dst, int* __restrict__ deg) {
    int e = blockIdx.x * 256 + threadIdx.x;
    if (e < NE) atomicAdd(&deg[dst[e]], 1);
}

__global__ __launch_bounds__(256) void k_bsum(const int* __restrict__ deg, int* __restrict__ bsum) {
    __shared__ int ls[256];
    const int t = threadIdx.x;
    const int idx = blockIdx.x * 256 + t;
    ls[t] = (idx < NN) ? deg[idx] : 0;
    __syncthreads();
#pragma unroll
    for (int off = 128; off; off >>= 1) {
        if (t < off) ls[t] += ls[t + off];
        __syncthreads();
    }
    if (t == 0) bsum[blockIdx.x] = ls[0];
}

__global__ __launch_bounds__(256) void k_scan2(const int* __restrict__ deg,
                                               const int* __restrict__ bsum,
                                               int* __restrict__ rowptr, int* __restrict__ cursor) {
    __shared__ int lb[256];
    __shared__ int ls[256];
    const int t = threadIdx.x, b = blockIdx.x;
    lb[t] = (t < NSB && t < b) ? bsum[t] : 0;
    const int idx = b * 256 + t;
    const int v = (idx < NN) ? deg[idx] : 0;
    ls[t] = v;
    __syncthreads();
#pragma unroll
    for (int off = 128; off; off >>= 1) {
        if (t < off) lb[t] += lb[t + off];
        __syncthreads();
    }
#pragma unroll
    for (int off = 1; off < 256; off <<= 1) {
        int u = (t >= off) ? ls[t - off] : 0;
        __syncthreads();
        ls[t] += u;
        __syncthreads();
    }
    if (idx < NN) {
        const int run = lb[0] + ls[t] - v;
        rowptr[idx] = run;
        cursor[idx] = run;
    }
    if (b == 0 && t == 0) rowptr[NN] = NE;
}

// also emits srcp = src in CSR order (kills one indirection in GAT)
__global__ __launch_bounds__(256) void k_perm(const int* __restrict__ dst, const int* __restrict__ src,
                                              int* __restrict__ cursor, int* __restrict__ eid,
                                              int* __restrict__ srcp) {
    int e = blockIdx.x * 256 + threadIdx.x;
    if (e < NE) {
        int p = atomicAdd(&cursor[dst[e]], 1);
        eid[p] = e;
        srcp[p] = src[e];
    }
}

// ---------------- one-time weight prep ----------------
__global__ __launch_bounds__(256) void k_wprep(const float* __restrict__ w3,
                                               const float* __restrict__ w2,
                                               const float* __restrict__ w1,
                                               const float* __restrict__ b1,
                                               const float* __restrict__ b3,
                                               unsigned short* __restrict__ w3t_g,
                                               unsigned short* __restrict__ w2t_g,
                                               unsigned short* __restrict__ w1p_g,
                                               unsigned short* __restrict__ b3t_g) {
    const int v = blockIdx.x * 256 + threadIdx.x;
    if (v < 64 * 512) {
        const int k = v >> 9, n = v & 511;
        const int byte = (n << 7) | ((k << 1) ^ ((n & 7) << 4));
        *(unsigned short*)((char*)w3t_g + byte) = f2bf(w3[v]);
    }
    if (v < 64 * 128) {
        const int o = v & 63, slot = v >> 6;
        const int ks = slot >> 4, lg2 = (slot >> 3) & 1, j = slot & 7;
        const int kp = (ks >> 1) * 32 + (j & 3) + 8 * (j >> 2) + 16 * (ks & 1) + 4 * lg2;
        const int byte = (o << 8) | ((slot << 1) ^ ((o & 7) << 4));
        *(unsigned short*)((char*)w2t_g + byte) = f2bf(w2[kp * 64 + o]);
    }
    if (v < 128 * 16) {
        const int j = v >> 4, k = v & 15;
        float val = (k < 3) ? w1[k * 128 + j] : (k == 3 ? b1[j] : 0.f);
        w1p_g[v] = f2bf(val);
    }
    if (v < 512) {
        const int i = v >> 5, o = v & 31;
        b3t_g[o * 16 + i] = f2bf(b3[v]);
    }
}

// ---------------- fused NNConv, all-MFMA, 32 edges per chunk ----------------
// R11: b2 seed moved out of registers — accumulators start at 0 and b2 is added from a
// 64-float LDS copy at the relu/pack step (broadcast reads). Frees 32 VGPRs -> no spill.
#define FUSED_GRID 256
#define NCHUNK (NE / 32)
__global__ __launch_bounds__(512, 1) void k_fused(
    const float* __restrict__ ea,
    const unsigned short* __restrict__ w1p_g,
    const unsigned short* __restrict__ w2t_g, const float* __restrict__ b2,
    const unsigned short* __restrict__ w3t_g, const unsigned short* __restrict__ b3t_g,
    const int* __restrict__ src, const float* __restrict__ x,
    unsigned short* __restrict__ msg)
{
    __shared__ __align__(16) unsigned short w3t[512 * 64];
    __shared__ __align__(16) unsigned short w2t[64 * 128];
    __shared__ __align__(16) unsigned short w1p[128 * 16];
    __shared__ __align__(16) unsigned short b3t[512];
    __shared__ __align__(16) float b2s[64];
    __shared__ __align__(16) unsigned slab[8][1024];

    const int t = threadIdx.x;
    {
        const uint4* g = (const uint4*)w3t_g;
        uint4* l = (uint4*)w3t;
        for (int v = t; v < 4096; v += 512) l[v] = g[v];
        const uint4* g2 = (const uint4*)w2t_g;
        uint4* l2 = (uint4*)w2t;
        for (int v = t; v < 1024; v += 512) l2[v] = g2[v];
    }
    if (t < 256) ((uint4*)w1p)[t] = ((const uint4*)w1p_g)[t];
    if (t < 64)  ((uint4*)b3t)[t] = ((const uint4*)b3t_g)[t];
    if (t < 64)  b2s[t] = b2[t];
    __syncthreads();

    const int wid = t >> 6, lane = t & 63;
    const int l31 = lane & 31, lg2 = lane >> 5;
    char* sw = (char*)slab[wid];
    const int swz = (l31 & 7) << 4;

    s16x8 w1pf[4];
#pragma unroll
    for (int n = 0; n < 4; ++n)
        w1pf[n] = *(const s16x8*)((const char*)w1p + ((n * 32 + l31) << 5) + lg2 * 16);
    s16x8 b3f = *(const s16x8*)((const char*)b3t + (l31 << 5) + lg2 * 16);

    for (int chunk = blockIdx.x * 8 + wid; chunk < NCHUNK; chunk += FUSED_GRID * 8) {
        const int e = chunk * 32 + l31;
        const int sn = src[e];
        const f32x4* __restrict__ xp = (const f32x4*)(x + (size_t)sn * 16);
        f32x4 x0 = xp[0], x1 = xp[1], x2 = xp[2], x3 = xp[3];
        const float ea0 = ea[e * 3], ea1 = ea[e * 3 + 1], ea2 = ea[e * 3 + 2];

        // ---- L1: 4 MFMAs, pack D into L2 B-fragments ----
        s16x8 eb = (s16x8){0, 0, 0, 0, 0, 0, 0, 0};
        if (lg2 == 0) {
            eb[0] = (short)f2bf(ea0); eb[1] = (short)f2bf(ea1);
            eb[2] = (short)f2bf(ea2); eb[3] = (short)0x3F80;  // 1.0
        }
        s16x8 hb[8];
#pragma unroll
        for (int n = 0; n < 4; ++n) {
            f32x16 d = {0.f};
            d = __builtin_amdgcn_mfma_f32_32x32x16_bf16(w1pf[n], eb, d, 0, 0, 0);
#pragma unroll
            for (int s = 0; s < 2; ++s)
#pragma unroll
                for (int j = 0; j < 8; ++j)
                    hb[2 * n + s][j] = (short)f2bf(fmaxf(d[(j & 3) + 4 * (j >> 2) + 8 * s], 0.f));
        }

        // ---- L2: h2 = relu(w2t @ h1 + b2), 16 MFMAs; b2 added at pack from LDS ----
        asm volatile("s_waitcnt lgkmcnt(0)" ::: "memory");  // prior iter slab reads done
#pragma unroll
        for (int nblk = 0; nblk < 2; ++nblk) {
            f32x16 a2 = {0.f};
            const char* __restrict__ w2row = (const char*)w2t + ((nblk * 32 + l31) << 8);
#pragma unroll
            for (int ks = 0; ks < 8; ++ks) {
                s16x8 a = *(const s16x8*)(w2row + ((ks * 32 + lg2 * 16) ^ swz));
                a2 = __builtin_amdgcn_mfma_f32_32x32x16_bf16(a, hb[ks], a2, 0, 0, 0);
            }
#pragma unroll
            for (int rh = 0; rh < 4; ++rh) {
                const f32x4 bv = *(const f32x4*)(b2s + nblk * 32 + rh * 8 + lg2 * 4);
                const int kb = nblk * 64 + rh * 16 + lg2 * 8;
                *(uint2*)(sw + l31 * 128 + (kb ^ swz)) =
                    pack_bf4(fmaxf(a2[rh * 4] + bv[0], 0.f), fmaxf(a2[rh * 4 + 1] + bv[1], 0.f),
                             fmaxf(a2[rh * 4 + 2] + bv[2], 0.f), fmaxf(a2[rh * 4 + 3] + bv[3], 0.f));
            }
        }
        asm volatile("s_waitcnt lgkmcnt(0)" ::: "memory");

        s16x8 wb[4];
#pragma unroll
        for (int ks = 0; ks < 4; ++ks)
            wb[ks] = *(const s16x8*)(sw + l31 * 128 + ((ks * 32 + lg2 * 16) ^ swz));

        s16x8 xbf;
        {
            f32x4 a0 = lg2 ? x2 : x0, a1 = lg2 ? x3 : x1;
#pragma unroll
            for (int i = 0; i < 4; ++i) {
                xbf[i] = (short)f2bf(a0[i]);
                xbf[i + 4] = (short)f2bf(a1[i]);
            }
        }
        f32x16 p = {0.f};
        p = __builtin_amdgcn_mfma_f32_32x32x16_bf16(b3f, xbf, p, 0, 0, 0);

#pragma unroll
        for (int nblk = 0; nblk < 16; ++nblk) {
            const char* __restrict__ arow = (const char*)w3t + ((nblk * 32 + l31) << 7);
            f32x16 d = {0.f};
#pragma unroll
            for (int ks = 0; ks < 4; ++ks) {
                s16x8 a = *(const s16x8*)(arow + ((ks * 32 + lg2 * 16) ^ swz));
                d = __builtin_amdgcn_mfma_f32_32x32x16_bf16(a, wb[ks], d, 0, 0, 0);
            }
            const float xs = (nblk < 4 ? x0 : nblk < 8 ? x1 : nblk < 12 ? x2 : x3)[nblk & 3];
#pragma unroll
            for (int r = 0; r < 16; ++r) p[r] = fmaf(xs, d[r], p[r]);
        }

        asm volatile("s_waitcnt lgkmcnt(0)" ::: "memory");
#pragma unroll
        for (int rh = 0; rh < 4; ++rh) {
            const int ob = rh * 16 + lg2 * 8;
            *(uint2*)(sw + l31 * 64 + (ob ^ ((l31 & 7) << 3))) =
                pack_bf4(p[rh * 4], p[rh * 4 + 1], p[rh * 4 + 2], p[rh * 4 + 3]);
        }
        asm volatile("s_waitcnt lgkmcnt(0)" ::: "memory");
#pragma unroll
        for (int q = 0; q < 2; ++q) {
            const int er = (lane >> 2) + q * 16;
            const int off = (lane & 3) * 16;
            const int s8 = (er & 7) << 3;
            uint2 a = *(const uint2*)(sw + er * 64 + (off ^ s8));
            uint2 b = *(const uint2*)(sw + er * 64 + ((off + 8) ^ s8));
            *(uint4*)((char*)msg + (size_t)chunk * 2048 + q * 1024 + lane * 16) =
                make_uint4(a.x, a.y, b.x, b.y);
        }
    }
}

// ---------------- aggregate msg by dst (CSR gather) + root transform ----------------
__global__ __launch_bounds__(256) void k_agg(
    const unsigned short* __restrict__ msg, const int* __restrict__ rowptr,
    const int* __restrict__ eid, const float* __restrict__ x,
    const float* __restrict__ rw, const float* __restrict__ cb, float* __restrict__ h1)
{
    const int gid = blockIdx.x * 256 + threadIdx.x;
    const int n = (gid >> 6) * 2 + ((gid & 63) >> 5);
    if (n >= NN) return;
    const int o = gid & 31;
    const int r0 = rowptr[n], r1 = rowptr[n + 1];
    float acc = 0.f;
    for (int j = r0; j < r1; ++j)
        acc += bf2f(msg[(size_t)eid[j] * 32 + o]);
    const float* __restrict__ xr = x + (size_t)n * 16;
    float root = cb[o];
#pragma unroll
    for (int i = 0; i < 16; ++i) root = fmaf(xr[i], rw[i * 32 + o], root);
    h1[(size_t)n * 32 + o] = fmaxf(acc + root, 0.f);
}

// ---------------- GAT: node transform (bf16 packed output) + attention coefficients ----------
template <int FI, bool BFIN>
__global__ __launch_bounds__(256) void k_gat_h(
    const void* __restrict__ hin, const float* __restrict__ W,
    const float* __restrict__ av_s, const float* __restrict__ av_d,
    unsigned* __restrict__ hbf, float* __restrict__ as_v, float* __restrict__ ad_v)
{
    const int n = blockIdx.x * 256 + threadIdx.x;
    if (n >= NN) return;
    float acc[64];
#pragma unroll
    for (int o = 0; o < 64; ++o) acc[o] = 0.f;

    float xv[FI];
    if constexpr (BFIN) {
        const uint4* __restrict__ hp = (const uint4*)((const unsigned*)hin + (size_t)n * (FI / 2));
#pragma unroll
        for (int q = 0; q < FI / 8; ++q) {
            uint4 v = hp[q];
            const unsigned w4[4] = {v.x, v.y, v.z, v.w};
#pragma unroll
            for (int c = 0; c < 4; ++c) {
                xv[q * 8 + 2 * c]     = bf2f((unsigned short)(w4[c] & 0xffff));
                xv[q * 8 + 2 * c + 1] = bf2f((unsigned short)(w4[c] >> 16));
            }
        }
    } else {
        const f32x4* __restrict__ hp = (const f32x4*)((const float*)hin + (size_t)n * FI);
#pragma unroll
        for (int q = 0; q < FI / 4; ++q) {
            f32x4 v = hp[q];
#pragma unroll
            for (int c = 0; c < 4; ++c) xv[q * 4 + c] = v[c];
        }
    }
#pragma unroll 2
    for (int i = 0; i < FI; ++i) {
        const float xi = xv[i];
        const float* __restrict__ wr = W + i * 64;
#pragma unroll
        for (int o = 0; o < 64; ++o) acc[o] = fmaf(xi, wr[o], acc[o]);
    }
    float s = 0.f, d = 0.f;
#pragma unroll
    for (int o = 0; o < 64; ++o) {
        s = fmaf(acc[o], av_s[o], s);
        d = fmaf(acc[o], av_d[o], d);
    }
    as_v[n] = s;
    ad_v[n] = d;
    uint4* __restrict__ op = (uint4*)(hbf + (size_t)n * 32);
#pragma unroll
    for (int q = 0; q < 8; ++q)
        op[q] = make_uint4(pack2(acc[8 * q], acc[8 * q + 1]), pack2(acc[8 * q + 2], acc[8 * q + 3]),
                           pack2(acc[8 * q + 4], acc[8 * q + 5]), pack2(acc[8 * q + 6], acc[8 * q + 7]));
}

// asp[j] = as_v[srcp[j]] : one random-gather pass; all softmax passes then stream
__global__ __launch_bounds__(256) void k_easrc(const int* __restrict__ srcp,
                                               const float* __restrict__ as_v,
                                               float* __restrict__ asp) {
    int j = blockIdx.x * 256 + threadIdx.x;
    if (j < NE) asp[j] = as_v[srcp[j]];
}

// ---------------- GAT: per-node softmax + weighted gather (4-edge ILP feature pass) --------
__global__ __launch_bounds__(256) void k_gat_node(
    const int* __restrict__ rowptr, const int* __restrict__ srcp, const float* __restrict__ asp,
    const unsigned* __restrict__ hbf, const float* __restrict__ as_v, const float* __restrict__ ad_v,
    const float* __restrict__ b, unsigned* __restrict__ outbf)
{
    const int n = (blockIdx.x * 256 + threadIdx.x) >> 6;
    if (n >= NN) return;
    const int lane = threadIdx.x & 63;
    const int fl = lane & 15, qw = lane >> 4;
    const int r0 = rowptr[n], r1 = rowptr[n + 1];
    const float adn = ad_v[n];
    const float l_self = lrelu(as_v[n] + adn);
    // pass 1: max (linear asp reads)
    float m = l_self;
    for (int j = r0 + lane; j < r1; j += 64)
        m = fmaxf(m, lrelu(asp[j] + adn));
#pragma unroll
    for (int off = 32; off; off >>= 1) m = fmaxf(m, __shfl_xor(m, off));
    // pass 2: denom (asp L1-hot)
    float s = 0.f;
    for (int j = r0 + lane; j < r1; j += 64)
        s += expf(lrelu(asp[j] + adn) - m);
#pragma unroll
    for (int off = 32; off; off >>= 1) s += __shfl_xor(s, off);
    const float w_self = expf(l_self - m);
    s += w_self;
    // pass 3: features — quarter-waves own alternate edges; 16 lanes x uint2 = one 128B row
    float a0 = 0.f, a1 = 0.f, a2 = 0.f, a3 = 0.f;
    if (qw == 0) {
        const uint2 hv = *(const uint2*)(hbf + (size_t)n * 32 + fl * 2);
        a0 = w_self * bf2f((unsigned short)(hv.x & 0xffff));
        a1 = w_self * bf2f((unsigned short)(hv.x >> 16));
        a2 = w_self * bf2f((unsigned short)(hv.y & 0xffff));
        a3 = w_self * bf2f((unsigned short)(hv.y >> 16));
    }
    for (int j = r0 + qw; j < r1; j += 4) {
        const int sn = srcp[j];
        const float w = expf(lrelu(asp[j] + adn) - m);
        const uint2 hv = *(const uint2*)(hbf + (size_t)sn * 32 + fl * 2);
        a0 = fmaf(w, bf2f((unsigned short)(hv.x & 0xffff)), a0);
        a1 = fmaf(w, bf2f((unsigned short)(hv.x >> 16)), a1);
        a2 = fmaf(w, bf2f((unsigned short)(hv.y & 0xffff)), a2);
        a3 = fmaf(w, bf2f((unsigned short)(hv.y >> 16)), a3);
    }
#pragma unroll
    for (int off = 16; off <= 32; off <<= 1) {
        a0 += __shfl_xor(a0, off);
        a1 += __shfl_xor(a1, off);
        a2 += __shfl_xor(a2, off);
        a3 += __shfl_xor(a3, off);
    }
    if (qw == 0) {
        const float v0 = fmaxf(a0 / s + b[4 * fl], 0.f);
        const float v1 = fmaxf(a1 / s + b[4 * fl + 1], 0.f);
        const float v2 = fmaxf(a2 / s + b[4 * fl + 2], 0.f);
        const float v3 = fmaxf(a3 / s + b[4 * fl + 3], 0.f);
        *(uint2*)(outbf + (size_t)n * 32 + fl * 2) = make_uint2(pack2(v0, v1), pack2(v2, v3));
    }
}

// ---------------- global mean pool (bf16 input) ----------------
__global__ __launch_bounds__(256) void k_pool1(
    const unsigned* __restrict__ hbf, const int* __restrict__ batch,
    float* __restrict__ gsum, float* __restrict__ gcnt)
{
    __shared__ float ls[NG * 64];
    __shared__ float lc[NG];
    for (int j = threadIdx.x; j < NG * 64; j += 256) ls[j] = 0.f;
    if (threadIdx.x < NG) lc[threadIdx.x] = 0.f;
    __syncthreads();
    const int base = blockIdx.x * 512;
    for (int idx = threadIdx.x; idx < 512 * 32; idx += 256) {
        const int nl = idx >> 5, f2 = idx & 31;
        const int n = base + nl;
        if (n < NN) {
            const int g = batch[n];
            const unsigned hv = hbf[(size_t)n * 32 + f2];
            atomicAdd(&ls[g * 64 + 2 * f2], bf2f((unsigned short)(hv & 0xffff)));
            atomicAdd(&ls[g * 64 + 2 * f2 + 1], bf2f((unsigned short)(hv >> 16)));
            if (f2 == 0) atomicAdd(&lc[g], 1.f);
        }
    }
    __syncthreads();
    for (int j = threadIdx.x; j < NG * 64; j += 256) atomicAdd(&gsum[j], ls[j]);
    if (threadIdx.x < NG) atomicAdd(&gcnt[threadIdx.x], lc[threadIdx.x]);
}

__global__ __launch_bounds__(256) void k_pool2(
    const float* __restrict__ gsum, const float* __restrict__ gcnt, float* __restrict__ out)
{
    const int idx = blockIdx.x * 256 + threadIdx.x;
    if (idx >= NG * 64) return;
    out[idx] = gsum[idx] / fmaxf(gcnt[idx >> 6], 1.f);
}

extern "C" void kernel_launch(void* const* d_in, const int* in_sizes, int n_in,
                              void* d_out, int out_size, void* d_ws, size_t ws_size,
                              hipStream_t stream)
{
    const float* x     = (const float*)d_in[0];
    const float* ea    = (const float*)d_in[1];
    const int*   ei    = (const int*)d_in[2];
    const int*   batch = (const int*)d_in[3];
    const float* w1 = (const float*)d_in[4];   const float* b1 = (const float*)d_in[5];
    const float* w2 = (const float*)d_in[6];   const float* b2 = (const float*)d_in[7];
    const float* w3 = (const float*)d_in[8];   const float* b3 = (const float*)d_in[9];
    const float* rw = (const float*)d_in[10];  const float* cb = (const float*)d_in[11];
    const float* g1w  = (const float*)d_in[12]; const float* g1as = (const float*)d_in[13];
    const float* g1ad = (const float*)d_in[14]; const float* g1b  = (const float*)d_in[15];
    const float* g2w  = (const float*)d_in[16]; const float* g2as = (const float*)d_in[17];
    const float* g2ad = (const float*)d_in[18]; const float* g2b  = (const float*)d_in[19];
    const int* src = ei;
    const int* dst = ei + NE;
    float* out = (float*)d_out;
    (void)in_sizes; (void)n_in; (void)out_size; (void)ws_size;

    char* ws = (char*)d_ws;
    size_t off = 0;
    auto alloc = [&](size_t bytes) -> char* {
        char* p = ws + off;
        off += (bytes + 255) & ~(size_t)255;
        return p;
    };
    int*  deg    = (int*)alloc((size_t)NN * 4);
    int*  cursor = (int*)alloc((size_t)NN * 4);
    int*  rowptr = (int*)alloc((size_t)(NN + 1) * 4);
    int*  bsum   = (int*)alloc((size_t)NSB * 4);
    int*  eid    = (int*)alloc((size_t)NE * 4);
    int*  srcp   = (int*)alloc((size_t)NE * 4);
    float* asp   = (float*)alloc((size_t)NE * 4);
    unsigned short* w3t_g = (unsigned short*)alloc((size_t)64 * 512 * 2);
    unsigned short* w2t_g = (unsigned short*)alloc((size_t)64 * 128 * 2);
    unsigned short* w1p_g = (unsigned short*)alloc((size_t)128 * 16 * 2);
    unsigned short* b3t_g = (unsigned short*)alloc((size_t)512 * 2);
    unsigned short* msg   = (unsigned short*)alloc((size_t)NE * 32 * 2);  // 25.6 MB
    float* h1    = (float*)alloc((size_t)NN * 32 * 4);
    unsigned* hT = (unsigned*)alloc((size_t)NN * 32 * 4);   // transformed h, bf16 packed
    unsigned* hC = (unsigned*)alloc((size_t)NN * 32 * 4);   // GAT1 output, bf16 packed
    unsigned* hD = (unsigned*)alloc((size_t)NN * 32 * 4);   // GAT2 output, bf16 packed
    float* as_v = (float*)alloc((size_t)NN * 4);
    float* ad_v = (float*)alloc((size_t)NN * 4);
    float* gsum = (float*)alloc((size_t)NG * 64 * 4);
    float* gcnt = (float*)alloc((size_t)NG * 4);

    hipMemsetAsync(deg, 0, (size_t)NN * 4, stream);
    hipMemsetAsync(gsum, 0, (size_t)NG * 64 * 4, stream);
    hipMemsetAsync(gcnt, 0, (size_t)NG * 4, stream);

    // CSR build
    k_hist<<<(NE + 255) / 256, 256, 0, stream>>>(dst, deg);
    k_bsum<<<NSB, 256, 0, stream>>>(deg, bsum);
    k_scan2<<<NSB, 256, 0, stream>>>(deg, bsum, rowptr, cursor);
    k_perm<<<(NE + 255) / 256, 256, 0, stream>>>(dst, src, cursor, eid, srcp);

    // NNConv (fused, all-MFMA)
    k_wprep<<<(64 * 512 + 255) / 256, 256, 0, stream>>>(w3, w2, w1, b1, b3,
                                                        w3t_g, w2t_g, w1p_g, b3t_g);
    k_fused<<<FUSED_GRID, 512, 0, stream>>>(ea, w1p_g, w2t_g, b2, w3t_g, b3t_g, src, x, msg);
    k_agg<<<(NN / 2 * 64 + 255) / 256 + 1, 256, 0, stream>>>(msg, rowptr, eid, x, rw, cb, h1);

    // GAT layer 1
    k_gat_h<32, false><<<(NN + 255) / 256, 256, 0, stream>>>(h1, g1w, g1as, g1ad, hT, as_v, ad_v);
    k_easrc<<<(NE + 255) / 256, 256, 0, stream>>>(srcp, as_v, asp);
    k_gat_node<<<(NN * 64 + 255) / 256, 256, 0, stream>>>(rowptr, srcp, asp, hT, as_v, ad_v, g1b, hC);

    // GAT layer 2
    k_gat_h<64, true><<<(NN + 255) / 256, 256, 0, stream>>>(hC, g2w, g2as, g2ad, hT, as_v, ad_v);
    k_easrc<<<(NE + 255) / 256, 256, 0, stream>>>(srcp, as_v, asp);
    k_gat_node<<<(NN * 64 + 255) / 256, 256, 0, stream>>>(rowptr, srcp, asp, hT, as_v, ad_v, g2b, hD);

    // pool
    k_pool1<<<(NN + 511) / 512, 256, 0, stream>>>(hD, batch, gsum, gcnt);
    k_pool2<<<(NG * 64 + 255) / 256, 256, 0, stream>>>(gsum, gcnt, out);
}